// Round 6
// baseline (2170.663 us; speedup 1.0000x reference)
//
#include <hip/hip_runtime.h>
#include <stdint.h>

#define NN 100000
#define EE 800000
#define GEMM_BX 1563          // ceil(100000/64)
#define WSTR 72               // padded bf16 LDS row stride (144 B: 2-way bank aliasing = free)
#define SSTR 68               // padded f32 LDS row stride for S-accum (272 B, 16B-aligned)
#define SLAB ((size_t)NN * 64)

typedef unsigned short u16;
typedef __attribute__((ext_vector_type(8))) short bf16x8;   // 8 bf16 = 4 VGPRs
typedef __attribute__((ext_vector_type(4))) float f32x4;

// f32 -> bf16 RNE
__device__ __forceinline__ uint32_t f2bf(float f) {
  uint32_t u = __float_as_uint(f);
  return (u + 0x7fffu + ((u >> 16) & 1u)) >> 16;
}

// ============================ threefry / noise ============================
__device__ __forceinline__ void tf_round(uint32_t& x0, uint32_t& x1, int r) {
  x0 += x1;
  x1 = (x1 << r) | (x1 >> (32 - r));
  x1 ^= x0;
}

// threefry2x32 with key (0, 42) == jax.random.key(42)
__device__ __forceinline__ void threefry_0_42(uint32_t c0, uint32_t c1,
                                              uint32_t& o0, uint32_t& o1) {
  const uint32_t ks0 = 0u, ks1 = 42u, ks2 = 0x1BD11BDAu ^ 42u;
  uint32_t x0 = c0 + ks0, x1 = c1 + ks1;
  tf_round(x0, x1, 13); tf_round(x0, x1, 15); tf_round(x0, x1, 26); tf_round(x0, x1, 6);
  x0 += ks1; x1 += ks2 + 1u;
  tf_round(x0, x1, 17); tf_round(x0, x1, 29); tf_round(x0, x1, 16); tf_round(x0, x1, 24);
  x0 += ks2; x1 += ks0 + 2u;
  tf_round(x0, x1, 13); tf_round(x0, x1, 15); tf_round(x0, x1, 26); tf_round(x0, x1, 6);
  x0 += ks0; x1 += ks1 + 3u;
  tf_round(x0, x1, 17); tf_round(x0, x1, 29); tf_round(x0, x1, 16); tf_round(x0, x1, 24);
  x0 += ks1; x1 += ks2 + 4u;
  tf_round(x0, x1, 13); tf_round(x0, x1, 15); tf_round(x0, x1, 26); tf_round(x0, x1, 6);
  x0 += ks2; x1 += ks0 + 5u;
  o0 = x0; o1 = x1;
}

// jax_threefry_partitionable noise (verified R2): bits = o0^o1 of threefry((0,42),(0,f))
// erfinv: Giles poly; w via hw v_log_f32 (fma keeps 1-u^2 exact); p2 branch
// (0.33%/lane) behind a wave-uniform __any vote — 81% of waves skip it.
__device__ __forceinline__ float noise_val(int s, int n, int d) {
  uint32_t f = (uint32_t)s * 6400000u + (uint32_t)n * 64u + (uint32_t)d;
  uint32_t o0, o1;
  threefry_0_42(0u, f, o0, o1);
  uint32_t bits = o0 ^ o1;
  float v = __uint_as_float((bits >> 9) | 0x3f800000u) - 1.0f;
  const float LO = -0.99999994f;
  float u = v * 2.0f + LO;
  u = fmaxf(u, LO);
  float w = -__logf(fmaf(-u, u, 1.0f));
  float ww = w - 2.5f;
  float p = 2.81022636e-08f;
  p = fmaf(p, ww, 3.43273939e-07f);
  p = fmaf(p, ww, -3.5233877e-06f);
  p = fmaf(p, ww, -4.39150654e-06f);
  p = fmaf(p, ww, 0.00021858087f);
  p = fmaf(p, ww, -0.00125372503f);
  p = fmaf(p, ww, -0.00417768164f);
  p = fmaf(p, ww, 0.246640727f);
  p = fmaf(p, ww, 1.50140941f);
  if (__any(w >= 5.0f)) {
    float ws = sqrtf(w) - 3.0f;
    float p2 = -0.000200214257f;
    p2 = fmaf(p2, ws, 0.000100950558f);
    p2 = fmaf(p2, ws, 0.00134934322f);
    p2 = fmaf(p2, ws, -0.00367342844f);
    p2 = fmaf(p2, ws, 0.00573950773f);
    p2 = fmaf(p2, ws, -0.0076224613f);
    p2 = fmaf(p2, ws, 0.00943887047f);
    p2 = fmaf(p2, ws, 1.00167406f);
    p2 = fmaf(p2, ws, 2.83297682f);
    p = (w < 5.0f) ? p : p2;
  }
  return 0.141421356f * (p * u);   // 0.1 * sqrt(2) * erfinv(u)
}

// ============================ mask dtype detection ============================
__device__ __forceinline__ int mask_at(const void* m, int e, int mode) {
  if (mode == 0) return ((const int*)m)[e] != 0;
  if (mode == 1) return ((const unsigned char*)m)[e] != 0;
  return ((const float*)m)[e] != 0.0f;
}

__global__ void k_detect(const unsigned* mw, int* mode_out) {
  __shared__ int nonbin, nonfloat;
  if (threadIdx.x == 0) { nonbin = 0; nonfloat = 0; }
  __syncthreads();
  int lb = 0, lf = 0;
  for (int i = threadIdx.x; i < 4096; i += 256) {
    unsigned v = mw[i];
    if (v > 1u) lb = 1;
    if (v != 0u && v != 0x3F800000u) lf = 1;
  }
  if (lb) atomicOr(&nonbin, 1);
  if (lf) atomicOr(&nonfloat, 1);
  __syncthreads();
  if (threadIdx.x == 0)
    mode_out[0] = (nonbin == 0) ? 0 : ((nonfloat == 0) ? 2 : 1);
}

// ============================ CSR build ============================
__global__ void k_count(const void* mask, const int* dst, int* cnt, const int* mode_p) {
  int e = blockIdx.x * 256 + threadIdx.x;
  if (e >= EE) return;
  if (mask_at(mask, e, *mode_p)) atomicAdd(&cnt[dst[e]], 1);
}

__global__ void k_scan_a(const int* cnt, int* blockSums) {
  __shared__ int sd[256];
  int t = threadIdx.x;
  int base = blockIdx.x * 1024 + t * 4;
  int s = 0;
  #pragma unroll
  for (int j = 0; j < 4; ++j) {
    int i = base + j;
    if (i < NN) s += cnt[i];
  }
  sd[t] = s;
  __syncthreads();
  for (int off = 128; off > 0; off >>= 1) {
    if (t < off) sd[t] += sd[t + off];
    __syncthreads();
  }
  if (t == 0) blockSums[blockIdx.x] = sd[0];
}

__global__ void k_scan_b(int* blockSums, int nb, int* total_out) {
  __shared__ int sd[128];
  int t = threadIdx.x;
  int v = (t < nb) ? blockSums[t] : 0;
  sd[t] = v;
  __syncthreads();
  for (int off = 1; off < 128; off <<= 1) {
    int x = (t >= off) ? sd[t - off] : 0;
    __syncthreads();
    sd[t] += x;
    __syncthreads();
  }
  if (t < nb) blockSums[t] = sd[t] - v;
  if (t == 0) total_out[0] = sd[127];
}

__global__ void k_scan_c(const int* cnt, const int* blockOffs, int* row_ptr,
                         int* cursor, float* cinv) {
  __shared__ int sd[256];
  int t = threadIdx.x;
  int base = blockIdx.x * 1024 + t * 4;
  int v[4], s = 0;
  #pragma unroll
  for (int j = 0; j < 4; ++j) {
    int i = base + j;
    v[j] = (i < NN) ? cnt[i] : 0;
    s += v[j];
  }
  sd[t] = s;
  __syncthreads();
  for (int off = 1; off < 256; off <<= 1) {
    int x = (t >= off) ? sd[t - off] : 0;
    __syncthreads();
    sd[t] += x;
    __syncthreads();
  }
  int excl = sd[t] - s + blockOffs[blockIdx.x];
  #pragma unroll
  for (int j = 0; j < 4; ++j) {
    int i = base + j;
    if (i < NN) {
      row_ptr[i] = excl;
      cursor[i] = excl;
      cinv[i] = 1.0f / fmaxf((float)v[j], 1.0f);
    }
    excl += v[j];
  }
}

// edata[p] = (src, dst) packed — one 8 B broadcast load per edge in k_layer
__global__ void k_fill(const void* mask, const int* src, const int* dst,
                       int* cursor, int2* edata, const int* mode_p) {
  int e = blockIdx.x * 256 + threadIdx.x;
  if (e >= EE) return;
  if (mask_at(mask, e, *mode_p)) {
    int d = dst[e];
    int p = atomicAdd(&cursor[d], 1);
    edata[p] = make_int2(src[e], d);
  }
}

// ============================ folded / transposed weights (bf16) ============================
// blocks 0,1: per-layer A1=WmT@Wu2, A2=WmB@Wu2, C1=msg_b@Wu2, Wu1T.
// block 2: WiT, WfT transposes. All weights emitted TRANSPOSED (WT[n][k]).
__global__ void k_prep(const float* msg_W, const float* msg_b, const float* upd_W,
                       const float* Wi, const float* Wf,
                       u16* Wu1T, u16* A1T, u16* A2T, float* C1,
                       u16* WiT, u16* WfT) {
  int t = threadIdx.x;
  if (blockIdx.x == 2) {
    for (int o = t; o < 4096; o += 256) {
      int k = o >> 6, n = o & 63;
      WiT[n * 64 + k] = (u16)f2bf(Wi[k * 64 + n]);
      WfT[n * 64 + k] = (u16)f2bf(Wf[k * 64 + n]);
    }
    return;
  }
  int l = blockIdx.x;
  const float* WmT = msg_W + l * 8192;
  const float* WmB = WmT + 4096;
  const float* Wu1 = upd_W + l * 8192;
  const float* Wu2 = Wu1 + 4096;
  for (int o = t; o < 4096; o += 256) {
    int a = o >> 6, b = o & 63;   // a = k-dim, b = n-dim
    float a1 = 0.f, a2 = 0.f;
    for (int j = 0; j < 64; ++j) {
      float w2 = Wu2[j * 64 + b];
      a1 = fmaf(WmT[a * 64 + j], w2, a1);
      a2 = fmaf(WmB[a * 64 + j], w2, a2);
    }
    A1T[l * 4096 + b * 64 + a]  = (u16)f2bf(a1);
    A2T[l * 4096 + b * 64 + a]  = (u16)f2bf(a2);
    Wu1T[l * 4096 + b * 64 + a] = (u16)f2bf(Wu1[a * 64 + b]);
  }
  if (t < 64) {
    float acc = 0.f;
    for (int j = 0; j < 64; ++j) acc = fmaf(msg_b[l * 64 + j], Wu2[j * 64 + t], acc);
    C1[l * 64 + t] = acc;
  }
}

// ============================ MFMA helpers ============================
// Wave w owns rows [w*16, w*16+16). A-frag: A[m=lane&15][k=quad*8+j].
// B-frag: B[k=quad*8+j][n=lane&15] == WT[n][k] rows. C/D: col=lane&15, row=quad*4+reg.
__device__ __forceinline__ void mm4(const u16* lW, int m16, int q,
                                    bf16x8 a0, bf16x8 a1, f32x4 (&acc)[4]) {
  #pragma unroll
  for (int nt = 0; nt < 4; ++nt) {
    const u16* wp = lW + (nt * 16 + m16) * WSTR + q * 8;
    bf16x8 b0 = *(const bf16x8*)(wp);
    bf16x8 b1 = *(const bf16x8*)(wp + 32);
    acc[nt] = __builtin_amdgcn_mfma_f32_16x16x32_bf16(a0, b0, acc[nt], 0, 0, 0);
    acc[nt] = __builtin_amdgcn_mfma_f32_16x16x32_bf16(a1, b1, acc[nt], 0, 0, 0);
  }
}

// stage 64x64 bf16 weight (unpadded global) into padded LDS (stride WSTR)
__device__ __forceinline__ void stage_W(const u16* __restrict__ WT, u16* lW) {
  int t = threadIdx.x;
  int r = t >> 2, seg = (t & 3) * 16;
  const uint4* p = (const uint4*)(WT + r * 64 + seg);
  uint4 a = p[0], b = p[1];
  *(uint4*)(lW + r * WSTR + seg) = a;
  *(uint4*)(lW + r * WSTR + seg + 8) = b;
}

// stage 64-row bf16 H tile into padded LDS
__device__ __forceinline__ void stage_H(const u16* __restrict__ Hin, int R0, u16* lT) {
  int t = threadIdx.x;
  int r = t >> 2, seg = (t & 3) * 16;
  int gr = R0 + r;
  uint4 a = {0, 0, 0, 0}, b = {0, 0, 0, 0};
  if (gr < NN) {
    const uint4* p = (const uint4*)(Hin + (size_t)gr * 64 + seg);
    a = p[0]; b = p[1];
  }
  *(uint4*)(lT + r * WSTR + seg) = a;
  *(uint4*)(lT + r * WSTR + seg + 8) = b;
}

// ============================ input projection ============================
// H[inst] = relu((x + noise_inst) @ Wi + bi), bf16 out
__global__ __launch_bounds__(256) void k_input(const float* __restrict__ x,
                                               const u16* __restrict__ WiT,
                                               const float* __restrict__ bi,
                                               u16* __restrict__ HoutB) {
  __shared__ __align__(16) u16 lT[64 * WSTR];
  __shared__ __align__(16) u16 lW[64 * WSTR];
  __shared__ float lB[64];
  int t = threadIdx.x;
  int R0 = blockIdx.x * 64;
  int inst = blockIdx.y;
  u16* Hout = HoutB + (size_t)inst * SLAB;
  {
    int r = t >> 2, seg = (t & 3) * 16;
    int gr = R0 + r;
    float v[16];
    if (gr < NN) {
      const float4* xp = (const float4*)(x + (size_t)gr * 64 + seg);
      #pragma unroll
      for (int qq = 0; qq < 4; ++qq) {
        float4 f = xp[qq];
        v[qq * 4 + 0] = f.x; v[qq * 4 + 1] = f.y;
        v[qq * 4 + 2] = f.z; v[qq * 4 + 3] = f.w;
      }
      if (inst > 0) {
        int s = inst - 1;
        #pragma unroll
        for (int j = 0; j < 16; ++j) v[j] += noise_val(s, gr, seg + j);
      }
    } else {
      #pragma unroll
      for (int j = 0; j < 16; ++j) v[j] = 0.f;
    }
    uint32_t pk[8];
    #pragma unroll
    for (int j = 0; j < 8; ++j)
      pk[j] = f2bf(v[2 * j]) | (f2bf(v[2 * j + 1]) << 16);
    uint4 A = {pk[0], pk[1], pk[2], pk[3]};
    uint4 B = {pk[4], pk[5], pk[6], pk[7]};
    *(uint4*)(lT + r * WSTR + seg) = A;
    *(uint4*)(lT + r * WSTR + seg + 8) = B;
  }
  stage_W(WiT, lW);
  if (t < 64) lB[t] = bi[t];
  __syncthreads();
  int l = t & 63, w = t >> 6;
  int m16 = l & 15, q = l >> 4;
  const u16* aRow = lT + (w * 16 + m16) * WSTR + q * 8;
  bf16x8 fa0 = *(const bf16x8*)(aRow);
  bf16x8 fa1 = *(const bf16x8*)(aRow + 32);
  f32x4 acc[4] = {{0.f, 0.f, 0.f, 0.f}, {0.f, 0.f, 0.f, 0.f},
                  {0.f, 0.f, 0.f, 0.f}, {0.f, 0.f, 0.f, 0.f}};
  mm4(lW, m16, q, fa0, fa1, acc);
  #pragma unroll
  for (int nt = 0; nt < 4; ++nt) {
    int c = nt * 16 + m16;
    #pragma unroll
    for (int r_ = 0; r_ < 4; ++r_) {
      int row = w * 16 + q * 4 + r_;
      int gr = R0 + row;
      if (gr < NN) {
        float vv = fmaxf(acc[nt][r_] + lB[c], 0.f);
        Hout[(size_t)gr * 64 + c] = (u16)f2bf(vv);
      }
    }
  }
}

// ============================ fused gather + layer update ============================
// Hn = relu(H@Wu1 + g*(H@A1) + (cinv*gatherSum(H))@A2 + b0 + g*c1)
// Gather is EDGE-PARALLEL: block's CSR edge range striped over 16 groups of
// 16 lanes (8 B of the neighbor row each), accumulated into an f32 LDS tile
// via ds_add_f32 atomics — all loads independent (no per-row serial chains).
__global__ __launch_bounds__(256) void k_layer(const u16* __restrict__ HinB,
                                               u16* __restrict__ HoutB,
                                               const int* __restrict__ row_ptr,
                                               const int2* __restrict__ edata,
                                               const int* __restrict__ cnt,
                                               const float* __restrict__ cinv,
                                               const u16* __restrict__ Wu1T,
                                               const u16* __restrict__ A1T,
                                               const u16* __restrict__ A2T,
                                               const float* __restrict__ b0,
                                               const float* __restrict__ c1) {
  __shared__ __align__(16) u16 lT[64 * WSTR];
  __shared__ __align__(16) u16 lW[64 * WSTR];
  __shared__ __align__(16) float lS[64 * SSTR];
  __shared__ float lB[128];
  __shared__ float lG[64];
  __shared__ float lCi[64];
  int t = threadIdx.x;
  int R0 = blockIdx.x * 64;
  const u16* Hin = HinB + (size_t)blockIdx.y * SLAB;
  u16* Hout = HoutB + (size_t)blockIdx.y * SLAB;

  stage_H(Hin, R0, lT);
  stage_W(Wu1T, lW);
  if (t < 64) {
    lB[t] = b0[t];
    lB[64 + t] = c1[t];
    int gr = R0 + t;
    lG[t] = (gr < NN && cnt[gr] > 0) ? 1.f : 0.f;
    lCi[t] = (gr < NN) ? cinv[gr] : 0.f;
  }
  #pragma unroll
  for (int i = t; i < 64 * SSTR; i += 256) lS[i] = 0.f;
  __syncthreads();

  // ---- edge-parallel gather ----
  {
    int e0 = row_ptr[R0];
    int rhi = (R0 + 64 < NN) ? (R0 + 64) : NN;
    int e1 = row_ptr[rhi];
    int g = t >> 4;
    int f0 = (t & 15) << 2;
    for (int e = e0 + g; e < e1; e += 16) {
      int2 ed = edata[e];                 // x = src, y = dst
      int r = ed.y - R0;
      uint2 p = *(const uint2*)(Hin + (size_t)ed.x * 64 + f0);
      float* sp = lS + r * SSTR + f0;
      atomicAdd(sp + 0, __uint_as_float(p.x << 16));
      atomicAdd(sp + 1, __uint_as_float(p.x & 0xffff0000u));
      atomicAdd(sp + 2, __uint_as_float(p.y << 16));
      atomicAdd(sp + 3, __uint_as_float(p.y & 0xffff0000u));
    }
  }
  __syncthreads();

  int l = t & 63, w = t >> 6;
  int m16 = l & 15, q = l >> 4;
  int arow = w * 16 + m16;
  const u16* aRow = lT + arow * WSTR + q * 8;
  bf16x8 fa0 = *(const bf16x8*)(aRow);
  bf16x8 fa1 = *(const bf16x8*)(aRow + 32);
  float gA = lG[arow];
  // S A-frag: read f32 accum, scale by cinv, convert to bf16
  bf16x8 fs0, fs1;
  {
    float ci = lCi[arow];
    const float* sRow = lS + arow * SSTR + q * 8;
    f32x4 sv0 = *(const f32x4*)(sRow);
    f32x4 sv1 = *(const f32x4*)(sRow + 4);
    union { uint32_t u[4]; bf16x8 v; } c0, c1u;
    #pragma unroll
    for (int j = 0; j < 4; ++j) {
      float e0 = sv0[j] * ci;
      float e1 = sv1[j] * ci;
      c0.u[j] = 0;  c1u.u[j] = 0;  // silence uninit
      c0.u[j] = f2bf(sv0[j] * ci);
      c1u.u[j] = f2bf(sv1[j] * ci);
      (void)e0; (void)e1;
    }
    // repack: we need 8 bf16 in order sv0[0..3], sv1[0..3]
    union { uint32_t u[4]; bf16x8 v; } pk;
    pk.u[0] = (c0.u[0] & 0xffffu) | (c0.u[1] << 16);
    pk.u[1] = (c0.u[2] & 0xffffu) | (c0.u[3] << 16);
    pk.u[2] = (c1u.u[0] & 0xffffu) | (c1u.u[1] << 16);
    pk.u[3] = (c1u.u[2] & 0xffffu) | (c1u.u[3] << 16);
    fs0 = pk.v;
    // second half: features q*8+4.. wait — fs0 covers k = q*8..q*8+8? No:
    // fs0 must hold 8 bf16 = k q*8..q*8+8 (sv0,sv1). fs1 unused split kept
    // for symmetry with mm4 (needs two frags: k-halves 0..32 / 32..64 per
    // MFMA pair). sRow spans 8 consecutive f32 = this lane's 8 k-values for
    // BOTH MFMAs? No — lane's A-frag for MFMA#1 is k=q*8..+8 of first 32?
    fs1 = pk.v;   // placeholder, fixed below
  }
  // NOTE: A-operand k-mapping for the two chained MFMAs: first mfma consumes
  // k=0..31 (lane gets k = q*8 .. q*8+7), second consumes k=32..63
  // (lane gets k = 32 + q*8 .. +7). So the two S fragments come from
  // lS[arow][q*8 ..] and lS[arow][32 + q*8 ..].
  {
    float ci = lCi[arow];
    const float* sRowB = lS + arow * SSTR + 32 + q * 8;
    f32x4 sv0 = *(const f32x4*)(sRowB);
    f32x4 sv1 = *(const f32x4*)(sRowB + 4);
    union { uint32_t u[4]; bf16x8 v; } pk;
    pk.u[0] = f2bf(sv0[0] * ci) | (f2bf(sv0[1] * ci) << 16);
    pk.u[1] = f2bf(sv0[2] * ci) | (f2bf(sv0[3] * ci) << 16);
    pk.u[2] = f2bf(sv1[0] * ci) | (f2bf(sv1[1] * ci) << 16);
    pk.u[3] = f2bf(sv1[2] * ci) | (f2bf(sv1[3] * ci) << 16);
    fs1 = pk.v;
  }

  f32x4 acc[4] = {{0.f, 0.f, 0.f, 0.f}, {0.f, 0.f, 0.f, 0.f},
                  {0.f, 0.f, 0.f, 0.f}, {0.f, 0.f, 0.f, 0.f}};
  mm4(lW, m16, q, fa0, fa1, acc);              // H @ Wu1
  __syncthreads();
  stage_W(A1T, lW);
  __syncthreads();
  bf16x8 zz = {0, 0, 0, 0, 0, 0, 0, 0};
  bf16x8 ga0 = (gA != 0.f) ? fa0 : zz;
  bf16x8 ga1 = (gA != 0.f) ? fa1 : zz;
  mm4(lW, m16, q, ga0, ga1, acc);              // g * (H @ A1)
  __syncthreads();
  stage_W(A2T, lW);
  __syncthreads();
  mm4(lW, m16, q, fs0, fs1, acc);              // (cinv*S) @ A2
  #pragma unroll
  for (int nt = 0; nt < 4; ++nt) {
    int c = nt * 16 + m16;
    #pragma unroll
    for (int r_ = 0; r_ < 4; ++r_) {
      int row = w * 16 + q * 4 + r_;
      int gr = R0 + row;
      if (gr < NN) {
        float vv = acc[nt][r_] + lB[c] + lG[row] * lB[64 + c];
        vv = fmaxf(vv, 0.f);
        Hout[(size_t)gr * 64 + c] = (u16)f2bf(vv);
      }
    }
  }
}

// ============================ final projection + variance (fused) ============================
__global__ __launch_bounds__(256) void k_final(const u16* __restrict__ HinB,
                                               const u16* __restrict__ WfT,
                                               const float* __restrict__ bfv,
                                               float* __restrict__ outCausal,
                                               float* __restrict__ out_u) {
  __shared__ __align__(16) u16 lT[64 * WSTR];
  __shared__ __align__(16) u16 lW[64 * WSTR];
  __shared__ float lB[64];
  int t = threadIdx.x;
  int R0 = blockIdx.x * 64;
  stage_W(WfT, lW);
  if (t < 64) lB[t] = bfv[t];
  int l = t & 63, w = t >> 6;
  int m16 = l & 15, q = l >> 4;
  float s1[16], s2[16];
  #pragma unroll
  for (int j = 0; j < 16; ++j) { s1[j] = 0.f; s2[j] = 0.f; }

  for (int inst = 0; inst < 5; ++inst) {
    __syncthreads();
    stage_H(HinB + (size_t)inst * SLAB, R0, lT);
    __syncthreads();
    const u16* aRow = lT + (w * 16 + m16) * WSTR + q * 8;
    bf16x8 fa0 = *(const bf16x8*)(aRow);
    bf16x8 fa1 = *(const bf16x8*)(aRow + 32);
    f32x4 acc[4] = {{0.f, 0.f, 0.f, 0.f}, {0.f, 0.f, 0.f, 0.f},
                    {0.f, 0.f, 0.f, 0.f}, {0.f, 0.f, 0.f, 0.f}};
    mm4(lW, m16, q, fa0, fa1, acc);
    #pragma unroll
    for (int nt = 0; nt < 4; ++nt) {
      int c = nt * 16 + m16;
      #pragma unroll
      for (int r_ = 0; r_ < 4; ++r_) {
        float z = acc[nt][r_] + lB[c];
        if (inst == 0) {
          int gr = R0 + w * 16 + q * 4 + r_;
          if (gr < NN) outCausal[(size_t)gr * 64 + c] = z;
        } else {
          s1[nt * 4 + r_] += z;
          s2[nt * 4 + r_] = fmaf(z, z, s2[nt * 4 + r_]);
        }
      }
    }
  }
  #pragma unroll
  for (int r_ = 0; r_ < 4; ++r_) {
    float pr = 0.f;
    #pragma unroll
    for (int nt = 0; nt < 4; ++nt) {
      float a = s1[nt * 4 + r_];
      pr += s2[nt * 4 + r_] - 0.25f * a * a;
    }
    #pragma unroll
    for (int msk = 1; msk < 16; msk <<= 1)
      pr += __shfl_xor(pr, msk, 64);
    if (m16 == 0) {
      int gr = R0 + w * 16 + q * 4 + r_;
      if (gr < NN) out_u[gr] = fmaxf(pr * (1.0f / 3.0f), 1e-6f);
    }
  }
}

// ============================ launch ============================
extern "C" void kernel_launch(void* const* d_in, const int* in_sizes, int n_in,
                              void* d_out, int out_size, void* d_ws, size_t ws_size,
                              hipStream_t stream) {
  const float* x      = (const float*)d_in[0];
  const int*   eidx   = (const int*)d_in[1];
  const void*  mask   = d_in[2];
  const float* Wi     = (const float*)d_in[3];
  const float* bi     = (const float*)d_in[4];
  const float* msg_W  = (const float*)d_in[5];
  const float* msg_b  = (const float*)d_in[6];
  const float* upd_W  = (const float*)d_in[7];
  const float* upd_b  = (const float*)d_in[8];
  const float* Wf     = (const float*)d_in[9];
  const float* bfv    = (const float*)d_in[10];

  const int* src = eidx;
  const int* dst = eidx + EE;

  char* ws = (char*)d_ws;
  size_t off = 0;
  auto alloc = [&](size_t bytes) -> void* {
    void* p = ws + off;
    off += (bytes + 255) & ~(size_t)255;
    return p;
  };

  int*   cnt     = (int*)alloc(NN * sizeof(int));
  float* cinv    = (float*)alloc(NN * sizeof(float));
  int*   row_ptr = (int*)alloc((NN + 1) * sizeof(int));
  int*   cursor  = (int*)alloc(NN * sizeof(int));
  int2*  edata   = (int2*)alloc(EE * sizeof(int2));
  int*   bsums   = (int*)alloc(128 * sizeof(int));
  int*   mode_p  = (int*)alloc(sizeof(int));
  u16*   Wu1T    = (u16*)alloc(2 * 4096 * sizeof(u16));
  u16*   A1T     = (u16*)alloc(2 * 4096 * sizeof(u16));
  u16*   A2T     = (u16*)alloc(2 * 4096 * sizeof(u16));
  u16*   WiT     = (u16*)alloc(4096 * sizeof(u16));
  u16*   WfT     = (u16*)alloc(4096 * sizeof(u16));
  float* C1      = (float*)alloc(2 * 64 * sizeof(float));
  u16*   HA      = (u16*)alloc(5 * SLAB * sizeof(u16));   // 64 MB
  u16*   HB      = (u16*)alloc(5 * SLAB * sizeof(u16));   // 64 MB

  float* out_causal = (float*)d_out;
  float* out_u      = (float*)d_out + SLAB;

  // ---- CSR build ----
  k_detect<<<1, 256, 0, stream>>>((const unsigned*)mask, mode_p);
  hipMemsetAsync(cnt, 0, NN * sizeof(int), stream);
  k_count<<<EE / 256, 256, 0, stream>>>(mask, dst, cnt, mode_p);
  const int SCAN_BLKS = (NN + 1023) / 1024;  // 98
  k_scan_a<<<SCAN_BLKS, 256, 0, stream>>>(cnt, bsums);
  k_scan_b<<<1, 128, 0, stream>>>(bsums, SCAN_BLKS, row_ptr + NN);
  k_scan_c<<<SCAN_BLKS, 256, 0, stream>>>(cnt, bsums, row_ptr, cursor, cinv);
  k_fill<<<EE / 256, 256, 0, stream>>>(mask, src, dst, cursor, edata, mode_p);

  // ---- weights ----
  k_prep<<<3, 256, 0, stream>>>(msg_W, msg_b, upd_W, Wi, Wf,
                                Wu1T, A1T, A2T, C1, WiT, WfT);

  // ---- 5 batched GNN passes ----
  dim3 g5(GEMM_BX, 5);
  k_input<<<g5, 256, 0, stream>>>(x, WiT, bi, HA);
  k_layer<<<g5, 256, 0, stream>>>(HA, HB, row_ptr, edata, cnt, cinv,
                                  Wu1T, A1T, A2T, upd_b, C1);
  k_layer<<<g5, 256, 0, stream>>>(HB, HA, row_ptr, edata, cnt, cinv,
                                  Wu1T + 4096, A1T + 4096, A2T + 4096,
                                  upd_b + 64, C1 + 64);
  k_final<<<GEMM_BX, 256, 0, stream>>>(HA, WfT, bfv, out_causal, out_u);

  (void)in_sizes; (void)n_in; (void)out_size; (void)ws_size;
}

// Round 7
// 674.790 us; speedup vs baseline: 3.2168x; 3.2168x over previous
//
#include <hip/hip_runtime.h>
#include <stdint.h>

#define NN 100000
#define EE 800000
#define GEMM_BX 1563          // ceil(100000/64)
#define WSTR 72               // padded bf16 LDS row stride (144 B: 2-way bank aliasing = free)
#define SLAB ((size_t)NN * 64)

typedef unsigned short u16;
typedef __attribute__((ext_vector_type(8))) short bf16x8;   // 8 bf16 = 4 VGPRs
typedef __attribute__((ext_vector_type(4))) float f32x4;

// f32 -> bf16 RNE
__device__ __forceinline__ uint32_t f2bf(float f) {
  uint32_t u = __float_as_uint(f);
  return (u + 0x7fffu + ((u >> 16) & 1u)) >> 16;
}

// ============================ threefry / noise ============================
__device__ __forceinline__ void tf_round(uint32_t& x0, uint32_t& x1, int r) {
  x0 += x1;
  x1 = (x1 << r) | (x1 >> (32 - r));
  x1 ^= x0;
}

// threefry2x32 with key (0, 42) == jax.random.key(42)
__device__ __forceinline__ void threefry_0_42(uint32_t c0, uint32_t c1,
                                              uint32_t& o0, uint32_t& o1) {
  const uint32_t ks0 = 0u, ks1 = 42u, ks2 = 0x1BD11BDAu ^ 42u;
  uint32_t x0 = c0 + ks0, x1 = c1 + ks1;
  tf_round(x0, x1, 13); tf_round(x0, x1, 15); tf_round(x0, x1, 26); tf_round(x0, x1, 6);
  x0 += ks1; x1 += ks2 + 1u;
  tf_round(x0, x1, 17); tf_round(x0, x1, 29); tf_round(x0, x1, 16); tf_round(x0, x1, 24);
  x0 += ks2; x1 += ks0 + 2u;
  tf_round(x0, x1, 13); tf_round(x0, x1, 15); tf_round(x0, x1, 26); tf_round(x0, x1, 6);
  x0 += ks0; x1 += ks1 + 3u;
  tf_round(x0, x1, 17); tf_round(x0, x1, 29); tf_round(x0, x1, 16); tf_round(x0, x1, 24);
  x0 += ks1; x1 += ks2 + 4u;
  tf_round(x0, x1, 13); tf_round(x0, x1, 15); tf_round(x0, x1, 26); tf_round(x0, x1, 6);
  x0 += ks2; x1 += ks0 + 5u;
  o0 = x0; o1 = x1;
}

// jax_threefry_partitionable noise (verified R2): bits = o0^o1 of threefry((0,42),(0,f))
// erfinv: Giles poly; w via hw v_log_f32 (fma keeps 1-u^2 exact); p2 branch
// (0.33%/lane) behind a wave-uniform __any vote — 81% of waves skip it.
__device__ __forceinline__ float noise_val(int s, int n, int d) {
  uint32_t f = (uint32_t)s * 6400000u + (uint32_t)n * 64u + (uint32_t)d;
  uint32_t o0, o1;
  threefry_0_42(0u, f, o0, o1);
  uint32_t bits = o0 ^ o1;
  float v = __uint_as_float((bits >> 9) | 0x3f800000u) - 1.0f;
  const float LO = -0.99999994f;
  float u = v * 2.0f + LO;
  u = fmaxf(u, LO);
  float w = -__logf(fmaf(-u, u, 1.0f));
  float ww = w - 2.5f;
  float p = 2.81022636e-08f;
  p = fmaf(p, ww, 3.43273939e-07f);
  p = fmaf(p, ww, -3.5233877e-06f);
  p = fmaf(p, ww, -4.39150654e-06f);
  p = fmaf(p, ww, 0.00021858087f);
  p = fmaf(p, ww, -0.00125372503f);
  p = fmaf(p, ww, -0.00417768164f);
  p = fmaf(p, ww, 0.246640727f);
  p = fmaf(p, ww, 1.50140941f);
  if (__any(w >= 5.0f)) {
    float ws = sqrtf(w) - 3.0f;
    float p2 = -0.000200214257f;
    p2 = fmaf(p2, ws, 0.000100950558f);
    p2 = fmaf(p2, ws, 0.00134934322f);
    p2 = fmaf(p2, ws, -0.00367342844f);
    p2 = fmaf(p2, ws, 0.00573950773f);
    p2 = fmaf(p2, ws, -0.0076224613f);
    p2 = fmaf(p2, ws, 0.00943887047f);
    p2 = fmaf(p2, ws, 1.00167406f);
    p2 = fmaf(p2, ws, 2.83297682f);
    p = (w < 5.0f) ? p : p2;
  }
  return 0.141421356f * (p * u);   // 0.1 * sqrt(2) * erfinv(u)
}

// ============================ mask dtype detection ============================
__device__ __forceinline__ int mask_at(const void* m, int e, int mode) {
  if (mode == 0) return ((const int*)m)[e] != 0;
  if (mode == 1) return ((const unsigned char*)m)[e] != 0;
  return ((const float*)m)[e] != 0.0f;
}

__global__ void k_detect(const unsigned* mw, int* mode_out) {
  __shared__ int nonbin, nonfloat;
  if (threadIdx.x == 0) { nonbin = 0; nonfloat = 0; }
  __syncthreads();
  int lb = 0, lf = 0;
  for (int i = threadIdx.x; i < 4096; i += 256) {
    unsigned v = mw[i];
    if (v > 1u) lb = 1;
    if (v != 0u && v != 0x3F800000u) lf = 1;
  }
  if (lb) atomicOr(&nonbin, 1);
  if (lf) atomicOr(&nonfloat, 1);
  __syncthreads();
  if (threadIdx.x == 0)
    mode_out[0] = (nonbin == 0) ? 0 : ((nonfloat == 0) ? 2 : 1);
}

// ============================ CSR build ============================
__global__ void k_count(const void* mask, const int* dst, int* cnt, const int* mode_p) {
  int e = blockIdx.x * 256 + threadIdx.x;
  if (e >= EE) return;
  if (mask_at(mask, e, *mode_p)) atomicAdd(&cnt[dst[e]], 1);
}

__global__ void k_scan_a(const int* cnt, int* blockSums) {
  __shared__ int sd[256];
  int t = threadIdx.x;
  int base = blockIdx.x * 1024 + t * 4;
  int s = 0;
  #pragma unroll
  for (int j = 0; j < 4; ++j) {
    int i = base + j;
    if (i < NN) s += cnt[i];
  }
  sd[t] = s;
  __syncthreads();
  for (int off = 128; off > 0; off >>= 1) {
    if (t < off) sd[t] += sd[t + off];
    __syncthreads();
  }
  if (t == 0) blockSums[blockIdx.x] = sd[0];
}

__global__ void k_scan_b(int* blockSums, int nb, int* total_out) {
  __shared__ int sd[128];
  int t = threadIdx.x;
  int v = (t < nb) ? blockSums[t] : 0;
  sd[t] = v;
  __syncthreads();
  for (int off = 1; off < 128; off <<= 1) {
    int x = (t >= off) ? sd[t - off] : 0;
    __syncthreads();
    sd[t] += x;
    __syncthreads();
  }
  if (t < nb) blockSums[t] = sd[t] - v;
  if (t == 0) total_out[0] = sd[127];
}

__global__ void k_scan_c(const int* cnt, const int* blockOffs, int* row_ptr,
                         int* cursor, float* cinv) {
  __shared__ int sd[256];
  int t = threadIdx.x;
  int base = blockIdx.x * 1024 + t * 4;
  int v[4], s = 0;
  #pragma unroll
  for (int j = 0; j < 4; ++j) {
    int i = base + j;
    v[j] = (i < NN) ? cnt[i] : 0;
    s += v[j];
  }
  sd[t] = s;
  __syncthreads();
  for (int off = 1; off < 256; off <<= 1) {
    int x = (t >= off) ? sd[t - off] : 0;
    __syncthreads();
    sd[t] += x;
    __syncthreads();
  }
  int excl = sd[t] - s + blockOffs[blockIdx.x];
  #pragma unroll
  for (int j = 0; j < 4; ++j) {
    int i = base + j;
    if (i < NN) {
      row_ptr[i] = excl;
      cursor[i] = excl;
      cinv[i] = 1.0f / fmaxf((float)v[j], 1.0f);
    }
    excl += v[j];
  }
}

__global__ void k_fill(const void* mask, const int* src, const int* dst,
                       int* cursor, int* col, const int* mode_p) {
  int e = blockIdx.x * 256 + threadIdx.x;
  if (e >= EE) return;
  if (mask_at(mask, e, *mode_p)) {
    int p = atomicAdd(&cursor[dst[e]], 1);
    col[p] = src[e];
  }
}

// ============================ folded / transposed weights (bf16) ============================
// blocks 0,1: per-layer A1=WmT@Wu2, A2=WmB@Wu2, C1=msg_b@Wu2, Wu1T.
// block 2: WiT, WfT transposes. All weights emitted TRANSPOSED (WT[n][k]).
__global__ void k_prep(const float* msg_W, const float* msg_b, const float* upd_W,
                       const float* Wi, const float* Wf,
                       u16* Wu1T, u16* A1T, u16* A2T, float* C1,
                       u16* WiT, u16* WfT) {
  int t = threadIdx.x;
  if (blockIdx.x == 2) {
    for (int o = t; o < 4096; o += 256) {
      int k = o >> 6, n = o & 63;
      WiT[n * 64 + k] = (u16)f2bf(Wi[k * 64 + n]);
      WfT[n * 64 + k] = (u16)f2bf(Wf[k * 64 + n]);
    }
    return;
  }
  int l = blockIdx.x;
  const float* WmT = msg_W + l * 8192;
  const float* WmB = WmT + 4096;
  const float* Wu1 = upd_W + l * 8192;
  const float* Wu2 = Wu1 + 4096;
  for (int o = t; o < 4096; o += 256) {
    int a = o >> 6, b = o & 63;   // a = k-dim, b = n-dim
    float a1 = 0.f, a2 = 0.f;
    for (int j = 0; j < 64; ++j) {
      float w2 = Wu2[j * 64 + b];
      a1 = fmaf(WmT[a * 64 + j], w2, a1);
      a2 = fmaf(WmB[a * 64 + j], w2, a2);
    }
    A1T[l * 4096 + b * 64 + a]  = (u16)f2bf(a1);
    A2T[l * 4096 + b * 64 + a]  = (u16)f2bf(a2);
    Wu1T[l * 4096 + b * 64 + a] = (u16)f2bf(Wu1[a * 64 + b]);
  }
  if (t < 64) {
    float acc = 0.f;
    for (int j = 0; j < 64; ++j) acc = fmaf(msg_b[l * 64 + j], Wu2[j * 64 + t], acc);
    C1[l * 64 + t] = acc;
  }
}

// ============================ MFMA helpers ============================
// Wave w owns rows [w*16, w*16+16). A-frag: A[m=lane&15][k=quad*8+j].
// B-frag: B[k=quad*8+j][n=lane&15] == WT[n][k] rows. C/D: col=lane&15, row=quad*4+reg.

// B-frags staged in padded LDS (k_input / k_final)
__device__ __forceinline__ void mm4(const u16* lW, int m16, int q,
                                    bf16x8 a0, bf16x8 a1, f32x4 (&acc)[4]) {
  #pragma unroll
  for (int nt = 0; nt < 4; ++nt) {
    const u16* wp = lW + (nt * 16 + m16) * WSTR + q * 8;
    bf16x8 b0 = *(const bf16x8*)(wp);
    bf16x8 b1 = *(const bf16x8*)(wp + 32);
    acc[nt] = __builtin_amdgcn_mfma_f32_16x16x32_bf16(a0, b0, acc[nt], 0, 0, 0);
    acc[nt] = __builtin_amdgcn_mfma_f32_16x16x32_bf16(a1, b1, acc[nt], 0, 0, 0);
  }
}

// B-frags straight from GLOBAL (unpadded WT[n][k], row stride 64) — weights are
// 8 KB/matrix, L1-resident; each 16-lane quad reads the same 16 B (broadcast).
__device__ __forceinline__ void mmg(const u16* __restrict__ WT, int m16, int q,
                                    bf16x8 a0, bf16x8 a1, f32x4 (&acc)[4]) {
  #pragma unroll
  for (int nt = 0; nt < 4; ++nt) {
    const u16* wp = WT + (nt * 16 + m16) * 64 + q * 8;
    bf16x8 b0 = *(const bf16x8*)(wp);
    bf16x8 b1 = *(const bf16x8*)(wp + 32);
    acc[nt] = __builtin_amdgcn_mfma_f32_16x16x32_bf16(a0, b0, acc[nt], 0, 0, 0);
    acc[nt] = __builtin_amdgcn_mfma_f32_16x16x32_bf16(a1, b1, acc[nt], 0, 0, 0);
  }
}

// stage 64x64 bf16 weight (unpadded global) into padded LDS (stride WSTR)
__device__ __forceinline__ void stage_W(const u16* __restrict__ WT, u16* lW) {
  int t = threadIdx.x;
  int r = t >> 2, seg = (t & 3) * 16;
  const uint4* p = (const uint4*)(WT + r * 64 + seg);
  uint4 a = p[0], b = p[1];
  *(uint4*)(lW + r * WSTR + seg) = a;
  *(uint4*)(lW + r * WSTR + seg + 8) = b;
}

// stage 64-row bf16 H tile into padded LDS
__device__ __forceinline__ void stage_H(const u16* __restrict__ Hin, int R0, u16* lT) {
  int t = threadIdx.x;
  int r = t >> 2, seg = (t & 3) * 16;
  int gr = R0 + r;
  uint4 a = {0, 0, 0, 0}, b = {0, 0, 0, 0};
  if (gr < NN) {
    const uint4* p = (const uint4*)(Hin + (size_t)gr * 64 + seg);
    a = p[0]; b = p[1];
  }
  *(uint4*)(lT + r * WSTR + seg) = a;
  *(uint4*)(lT + r * WSTR + seg + 8) = b;
}

// ============================ input projection ============================
// H[inst] = relu((x + noise_inst) @ Wi + bi), bf16 out
__global__ __launch_bounds__(256) void k_input(const float* __restrict__ x,
                                               const u16* __restrict__ WiT,
                                               const float* __restrict__ bi,
                                               u16* __restrict__ HoutB) {
  __shared__ __align__(16) u16 lT[64 * WSTR];
  __shared__ __align__(16) u16 lW[64 * WSTR];
  __shared__ float lB[64];
  int t = threadIdx.x;
  int R0 = blockIdx.x * 64;
  int inst = blockIdx.y;
  u16* Hout = HoutB + (size_t)inst * SLAB;
  {
    int r = t >> 2, seg = (t & 3) * 16;
    int gr = R0 + r;
    float v[16];
    if (gr < NN) {
      const float4* xp = (const float4*)(x + (size_t)gr * 64 + seg);
      #pragma unroll
      for (int qq = 0; qq < 4; ++qq) {
        float4 f = xp[qq];
        v[qq * 4 + 0] = f.x; v[qq * 4 + 1] = f.y;
        v[qq * 4 + 2] = f.z; v[qq * 4 + 3] = f.w;
      }
      if (inst > 0) {
        int s = inst - 1;
        #pragma unroll
        for (int j = 0; j < 16; ++j) v[j] += noise_val(s, gr, seg + j);
      }
    } else {
      #pragma unroll
      for (int j = 0; j < 16; ++j) v[j] = 0.f;
    }
    uint32_t pk[8];
    #pragma unroll
    for (int j = 0; j < 8; ++j)
      pk[j] = f2bf(v[2 * j]) | (f2bf(v[2 * j + 1]) << 16);
    uint4 A = {pk[0], pk[1], pk[2], pk[3]};
    uint4 B = {pk[4], pk[5], pk[6], pk[7]};
    *(uint4*)(lT + r * WSTR + seg) = A;
    *(uint4*)(lT + r * WSTR + seg + 8) = B;
  }
  stage_W(WiT, lW);
  if (t < 64) lB[t] = bi[t];
  __syncthreads();
  int l = t & 63, w = t >> 6;
  int m16 = l & 15, q = l >> 4;
  const u16* aRow = lT + (w * 16 + m16) * WSTR + q * 8;
  bf16x8 fa0 = *(const bf16x8*)(aRow);
  bf16x8 fa1 = *(const bf16x8*)(aRow + 32);
  f32x4 acc[4] = {{0.f, 0.f, 0.f, 0.f}, {0.f, 0.f, 0.f, 0.f},
                  {0.f, 0.f, 0.f, 0.f}, {0.f, 0.f, 0.f, 0.f}};
  mm4(lW, m16, q, fa0, fa1, acc);
  #pragma unroll
  for (int nt = 0; nt < 4; ++nt) {
    int c = nt * 16 + m16;
    #pragma unroll
    for (int r_ = 0; r_ < 4; ++r_) {
      int row = w * 16 + q * 4 + r_;
      int gr = R0 + row;
      if (gr < NN) {
        float vv = fmaxf(acc[nt][r_] + lB[c], 0.f);
        Hout[(size_t)gr * 64 + c] = (u16)f2bf(vv);
      }
    }
  }
}

// ============================ fused gather + layer update ============================
// Hn = relu(H@Wu1 + g*(H@A1) + (cinv*gatherSum(H))@A2 + b0 + g*c1)
// R5's proven row-serial gather (4 rows in flight per wave, 4-deep unroll,
// NO atomics — R6 showed LDS atomics serialize the load pipeline).
// A-frags and B-frags read directly from global (H already bf16; weights
// L1-resident) — only the gathered S-tile lives in LDS -> ONE barrier.
__global__ __launch_bounds__(256) void k_layer(const u16* __restrict__ HinB,
                                               u16* __restrict__ HoutB,
                                               const int* __restrict__ row_ptr,
                                               const int* __restrict__ col,
                                               const int* __restrict__ cnt,
                                               const float* __restrict__ cinv,
                                               const u16* __restrict__ Wu1T,
                                               const u16* __restrict__ A1T,
                                               const u16* __restrict__ A2T,
                                               const float* __restrict__ b0,
                                               const float* __restrict__ c1) {
  __shared__ __align__(16) u16 lS[64 * WSTR];
  __shared__ float lB[128];
  __shared__ float lG[64];
  int t = threadIdx.x;
  int R0 = blockIdx.x * 64;
  const u16* Hin = HinB + (size_t)blockIdx.y * SLAB;
  u16* Hout = HoutB + (size_t)blockIdx.y * SLAB;

  if (t < 64) {
    lB[t] = b0[t];
    lB[64 + t] = c1[t];
    int gr = R0 + t;
    lG[t] = (gr < NN && cnt[gr] > 0) ? 1.f : 0.f;
  }
  // gather bf16 neighbor rows: 16 lanes x 8 B per edge row
  {
    int wv = t >> 6, sub = (t >> 4) & 3, f0 = (t & 15) << 2;
    const u16* hb = Hin + f0;
    #pragma unroll
    for (int b = 0; b < 4; ++b) {
      int r = wv * 16 + b * 4 + sub;
      int n = R0 + r;
      float g0 = 0.f, g1 = 0.f, g2 = 0.f, g3 = 0.f;
      if (n < NN) {
        int e = row_ptr[n], end = row_ptr[n + 1];
        for (; e + 4 <= end; e += 4) {
          uint2 p0 = *(const uint2*)(hb + (size_t)col[e] * 64);
          uint2 p1 = *(const uint2*)(hb + (size_t)col[e + 1] * 64);
          uint2 p2 = *(const uint2*)(hb + (size_t)col[e + 2] * 64);
          uint2 p3 = *(const uint2*)(hb + (size_t)col[e + 3] * 64);
          g0 += (__uint_as_float(p0.x << 16) + __uint_as_float(p1.x << 16)) +
                (__uint_as_float(p2.x << 16) + __uint_as_float(p3.x << 16));
          g1 += (__uint_as_float(p0.x & 0xffff0000u) + __uint_as_float(p1.x & 0xffff0000u)) +
                (__uint_as_float(p2.x & 0xffff0000u) + __uint_as_float(p3.x & 0xffff0000u));
          g2 += (__uint_as_float(p0.y << 16) + __uint_as_float(p1.y << 16)) +
                (__uint_as_float(p2.y << 16) + __uint_as_float(p3.y << 16));
          g3 += (__uint_as_float(p0.y & 0xffff0000u) + __uint_as_float(p1.y & 0xffff0000u)) +
                (__uint_as_float(p2.y & 0xffff0000u) + __uint_as_float(p3.y & 0xffff0000u));
        }
        for (; e < end; ++e) {
          uint2 p0 = *(const uint2*)(hb + (size_t)col[e] * 64);
          g0 += __uint_as_float(p0.x << 16);
          g1 += __uint_as_float(p0.x & 0xffff0000u);
          g2 += __uint_as_float(p0.y << 16);
          g3 += __uint_as_float(p0.y & 0xffff0000u);
        }
        float ci = cinv[n];
        g0 *= ci; g1 *= ci; g2 *= ci; g3 *= ci;
      }
      uint2 pk;
      pk.x = f2bf(g0) | (f2bf(g1) << 16);
      pk.y = f2bf(g2) | (f2bf(g3) << 16);
      *(uint2*)(lS + r * WSTR + f0) = pk;
    }
  }
  __syncthreads();

  int l = t & 63, w = t >> 6;
  int m16 = l & 15, q = l >> 4;
  int arow = w * 16 + m16;
  int gra = R0 + arow;
  // A-frags straight from global bf16 H (16 B contiguous per frag)
  bf16x8 fa0, fa1;
  if (gra < NN) {
    const u16* ap = Hin + (size_t)gra * 64 + q * 8;
    fa0 = *(const bf16x8*)(ap);
    fa1 = *(const bf16x8*)(ap + 32);
  } else {
    bf16x8 zz = {0, 0, 0, 0, 0, 0, 0, 0};
    fa0 = zz; fa1 = zz;
  }
  float gA = lG[arow];
  const u16* sRow = lS + arow * WSTR + q * 8;
  bf16x8 fs0 = *(const bf16x8*)(sRow);
  bf16x8 fs1 = *(const bf16x8*)(sRow + 32);

  f32x4 acc[4] = {{0.f, 0.f, 0.f, 0.f}, {0.f, 0.f, 0.f, 0.f},
                  {0.f, 0.f, 0.f, 0.f}, {0.f, 0.f, 0.f, 0.f}};
  mmg(Wu1T, m16, q, fa0, fa1, acc);            // H @ Wu1
  bf16x8 zz = {0, 0, 0, 0, 0, 0, 0, 0};
  bf16x8 ga0 = (gA != 0.f) ? fa0 : zz;
  bf16x8 ga1 = (gA != 0.f) ? fa1 : zz;
  mmg(A1T, m16, q, ga0, ga1, acc);             // g * (H @ A1)
  mmg(A2T, m16, q, fs0, fs1, acc);             // (cinv*S) @ A2
  #pragma unroll
  for (int nt = 0; nt < 4; ++nt) {
    int c = nt * 16 + m16;
    #pragma unroll
    for (int r_ = 0; r_ < 4; ++r_) {
      int row = w * 16 + q * 4 + r_;
      int gr = R0 + row;
      if (gr < NN) {
        float vv = acc[nt][r_] + lB[c] + lG[row] * lB[64 + c];
        vv = fmaxf(vv, 0.f);
        Hout[(size_t)gr * 64 + c] = (u16)f2bf(vv);
      }
    }
  }
}

// ============================ final projection + variance (fused) ============================
__global__ __launch_bounds__(256) void k_final(const u16* __restrict__ HinB,
                                               const u16* __restrict__ WfT,
                                               const float* __restrict__ bfv,
                                               float* __restrict__ outCausal,
                                               float* __restrict__ out_u) {
  __shared__ __align__(16) u16 lT[64 * WSTR];
  __shared__ __align__(16) u16 lW[64 * WSTR];
  __shared__ float lB[64];
  int t = threadIdx.x;
  int R0 = blockIdx.x * 64;
  stage_W(WfT, lW);
  if (t < 64) lB[t] = bfv[t];
  int l = t & 63, w = t >> 6;
  int m16 = l & 15, q = l >> 4;
  float s1[16], s2[16];
  #pragma unroll
  for (int j = 0; j < 16; ++j) { s1[j] = 0.f; s2[j] = 0.f; }

  for (int inst = 0; inst < 5; ++inst) {
    __syncthreads();
    stage_H(HinB + (size_t)inst * SLAB, R0, lT);
    __syncthreads();
    const u16* aRow = lT + (w * 16 + m16) * WSTR + q * 8;
    bf16x8 fa0 = *(const bf16x8*)(aRow);
    bf16x8 fa1 = *(const bf16x8*)(aRow + 32);
    f32x4 acc[4] = {{0.f, 0.f, 0.f, 0.f}, {0.f, 0.f, 0.f, 0.f},
                    {0.f, 0.f, 0.f, 0.f}, {0.f, 0.f, 0.f, 0.f}};
    mm4(lW, m16, q, fa0, fa1, acc);
    #pragma unroll
    for (int nt = 0; nt < 4; ++nt) {
      int c = nt * 16 + m16;
      #pragma unroll
      for (int r_ = 0; r_ < 4; ++r_) {
        float z = acc[nt][r_] + lB[c];
        if (inst == 0) {
          int gr = R0 + w * 16 + q * 4 + r_;
          if (gr < NN) outCausal[(size_t)gr * 64 + c] = z;
        } else {
          s1[nt * 4 + r_] += z;
          s2[nt * 4 + r_] = fmaf(z, z, s2[nt * 4 + r_]);
        }
      }
    }
  }
  #pragma unroll
  for (int r_ = 0; r_ < 4; ++r_) {
    float pr = 0.f;
    #pragma unroll
    for (int nt = 0; nt < 4; ++nt) {
      float a = s1[nt * 4 + r_];
      pr += s2[nt * 4 + r_] - 0.25f * a * a;
    }
    #pragma unroll
    for (int msk = 1; msk < 16; msk <<= 1)
      pr += __shfl_xor(pr, msk, 64);
    if (m16 == 0) {
      int gr = R0 + w * 16 + q * 4 + r_;
      if (gr < NN) out_u[gr] = fmaxf(pr * (1.0f / 3.0f), 1e-6f);
    }
  }
}

// ============================ launch ============================
extern "C" void kernel_launch(void* const* d_in, const int* in_sizes, int n_in,
                              void* d_out, int out_size, void* d_ws, size_t ws_size,
                              hipStream_t stream) {
  const float* x      = (const float*)d_in[0];
  const int*   eidx   = (const int*)d_in[1];
  const void*  mask   = d_in[2];
  const float* Wi     = (const float*)d_in[3];
  const float* bi     = (const float*)d_in[4];
  const float* msg_W  = (const float*)d_in[5];
  const float* msg_b  = (const float*)d_in[6];
  const float* upd_W  = (const float*)d_in[7];
  const float* upd_b  = (const float*)d_in[8];
  const float* Wf     = (const float*)d_in[9];
  const float* bfv    = (const float*)d_in[10];

  const int* src = eidx;
  const int* dst = eidx + EE;

  char* ws = (char*)d_ws;
  size_t off = 0;
  auto alloc = [&](size_t bytes) -> void* {
    void* p = ws + off;
    off += (bytes + 255) & ~(size_t)255;
    return p;
  };

  int*   cnt     = (int*)alloc(NN * sizeof(int));
  float* cinv    = (float*)alloc(NN * sizeof(float));
  int*   row_ptr = (int*)alloc((NN + 1) * sizeof(int));
  int*   cursor  = (int*)alloc(NN * sizeof(int));
  int*   col     = (int*)alloc(EE * sizeof(int));
  int*   bsums   = (int*)alloc(128 * sizeof(int));
  int*   mode_p  = (int*)alloc(sizeof(int));
  u16*   Wu1T    = (u16*)alloc(2 * 4096 * sizeof(u16));
  u16*   A1T     = (u16*)alloc(2 * 4096 * sizeof(u16));
  u16*   A2T     = (u16*)alloc(2 * 4096 * sizeof(u16));
  u16*   WiT     = (u16*)alloc(4096 * sizeof(u16));
  u16*   WfT     = (u16*)alloc(4096 * sizeof(u16));
  float* C1      = (float*)alloc(2 * 64 * sizeof(float));
  u16*   HA      = (u16*)alloc(5 * SLAB * sizeof(u16));   // 64 MB
  u16*   HB      = (u16*)alloc(5 * SLAB * sizeof(u16));   // 64 MB

  float* out_causal = (float*)d_out;
  float* out_u      = (float*)d_out + SLAB;

  // ---- CSR build ----
  k_detect<<<1, 256, 0, stream>>>((const unsigned*)mask, mode_p);
  hipMemsetAsync(cnt, 0, NN * sizeof(int), stream);
  k_count<<<EE / 256, 256, 0, stream>>>(mask, dst, cnt, mode_p);
  const int SCAN_BLKS = (NN + 1023) / 1024;  // 98
  k_scan_a<<<SCAN_BLKS, 256, 0, stream>>>(cnt, bsums);
  k_scan_b<<<1, 128, 0, stream>>>(bsums, SCAN_BLKS, row_ptr + NN);
  k_scan_c<<<SCAN_BLKS, 256, 0, stream>>>(cnt, bsums, row_ptr, cursor, cinv);
  k_fill<<<EE / 256, 256, 0, stream>>>(mask, src, dst, cursor, col, mode_p);

  // ---- weights ----
  k_prep<<<3, 256, 0, stream>>>(msg_W, msg_b, upd_W, Wi, Wf,
                                Wu1T, A1T, A2T, C1, WiT, WfT);

  // ---- 5 batched GNN passes ----
  dim3 g5(GEMM_BX, 5);
  k_input<<<g5, 256, 0, stream>>>(x, WiT, bi, HA);
  k_layer<<<g5, 256, 0, stream>>>(HA, HB, row_ptr, col, cnt, cinv,
                                  Wu1T, A1T, A2T, upd_b, C1);
  k_layer<<<g5, 256, 0, stream>>>(HB, HA, row_ptr, col, cnt, cinv,
                                  Wu1T + 4096, A1T + 4096, A2T + 4096,
                                  upd_b + 64, C1 + 64);
  k_final<<<GEMM_BX, 256, 0, stream>>>(HA, WfT, bfv, out_causal, out_u);

  (void)in_sizes; (void)n_in; (void)out_size; (void)ws_size;
}

// Round 8
// 527.162 us; speedup vs baseline: 4.1176x; 1.2800x over previous
//
#include <hip/hip_runtime.h>
#include <stdint.h>

#define NN 100000
#define EE 800000
#define GEMM_BX 1563          // ceil(100000/64)
#define WSTR 72               // padded bf16 LDS row stride (144 B: 2-way bank aliasing = free)
#define SLAB ((size_t)NN * 64)

typedef unsigned short u16;
typedef __attribute__((ext_vector_type(8))) short bf16x8;   // 8 bf16 = 4 VGPRs
typedef __attribute__((ext_vector_type(4))) float f32x4;

// f32 -> bf16 RNE
__device__ __forceinline__ uint32_t f2bf(float f) {
  uint32_t u = __float_as_uint(f);
  return (u + 0x7fffu + ((u >> 16) & 1u)) >> 16;
}

// ============================ threefry / noise ============================
__device__ __forceinline__ void tf_round(uint32_t& x0, uint32_t& x1, int r) {
  x0 += x1;
  x1 = (x1 << r) | (x1 >> (32 - r));
  x1 ^= x0;
}

// threefry2x32 with key (0, 42) == jax.random.key(42)
__device__ __forceinline__ void threefry_0_42(uint32_t c0, uint32_t c1,
                                              uint32_t& o0, uint32_t& o1) {
  const uint32_t ks0 = 0u, ks1 = 42u, ks2 = 0x1BD11BDAu ^ 42u;
  uint32_t x0 = c0 + ks0, x1 = c1 + ks1;
  tf_round(x0, x1, 13); tf_round(x0, x1, 15); tf_round(x0, x1, 26); tf_round(x0, x1, 6);
  x0 += ks1; x1 += ks2 + 1u;
  tf_round(x0, x1, 17); tf_round(x0, x1, 29); tf_round(x0, x1, 16); tf_round(x0, x1, 24);
  x0 += ks2; x1 += ks0 + 2u;
  tf_round(x0, x1, 13); tf_round(x0, x1, 15); tf_round(x0, x1, 26); tf_round(x0, x1, 6);
  x0 += ks0; x1 += ks1 + 3u;
  tf_round(x0, x1, 17); tf_round(x0, x1, 29); tf_round(x0, x1, 16); tf_round(x0, x1, 24);
  x0 += ks1; x1 += ks2 + 4u;
  tf_round(x0, x1, 13); tf_round(x0, x1, 15); tf_round(x0, x1, 26); tf_round(x0, x1, 6);
  x0 += ks2; x1 += ks0 + 5u;
  o0 = x0; o1 = x1;
}

// jax_threefry_partitionable noise (verified R2): bits = o0^o1 of threefry((0,42),(0,f))
__device__ __forceinline__ float noise_val(int s, int n, int d) {
  uint32_t f = (uint32_t)s * 6400000u + (uint32_t)n * 64u + (uint32_t)d;
  uint32_t o0, o1;
  threefry_0_42(0u, f, o0, o1);
  uint32_t bits = o0 ^ o1;
  float v = __uint_as_float((bits >> 9) | 0x3f800000u) - 1.0f;
  const float LO = -0.99999994f;
  float u = v * 2.0f + LO;
  u = fmaxf(u, LO);
  float w = -__logf(fmaf(-u, u, 1.0f));
  float ww = w - 2.5f;
  float p = 2.81022636e-08f;
  p = fmaf(p, ww, 3.43273939e-07f);
  p = fmaf(p, ww, -3.5233877e-06f);
  p = fmaf(p, ww, -4.39150654e-06f);
  p = fmaf(p, ww, 0.00021858087f);
  p = fmaf(p, ww, -0.00125372503f);
  p = fmaf(p, ww, -0.00417768164f);
  p = fmaf(p, ww, 0.246640727f);
  p = fmaf(p, ww, 1.50140941f);
  if (__any(w >= 5.0f)) {
    float ws = sqrtf(w) - 3.0f;
    float p2 = -0.000200214257f;
    p2 = fmaf(p2, ws, 0.000100950558f);
    p2 = fmaf(p2, ws, 0.00134934322f);
    p2 = fmaf(p2, ws, -0.00367342844f);
    p2 = fmaf(p2, ws, 0.00573950773f);
    p2 = fmaf(p2, ws, -0.0076224613f);
    p2 = fmaf(p2, ws, 0.00943887047f);
    p2 = fmaf(p2, ws, 1.00167406f);
    p2 = fmaf(p2, ws, 2.83297682f);
    p = (w < 5.0f) ? p : p2;
  }
  return 0.141421356f * (p * u);   // 0.1 * sqrt(2) * erfinv(u)
}

// ============================ mask dtype detection ============================
__device__ __forceinline__ int mask_at(const void* m, int e, int mode) {
  if (mode == 0) return ((const int*)m)[e] != 0;
  if (mode == 1) return ((const unsigned char*)m)[e] != 0;
  return ((const float*)m)[e] != 0.0f;
}

__global__ void k_detect(const unsigned* mw, int* mode_out) {
  __shared__ int nonbin, nonfloat;
  if (threadIdx.x == 0) { nonbin = 0; nonfloat = 0; }
  __syncthreads();
  int lb = 0, lf = 0;
  for (int i = threadIdx.x; i < 4096; i += 256) {
    unsigned v = mw[i];
    if (v > 1u) lb = 1;
    if (v != 0u && v != 0x3F800000u) lf = 1;
  }
  if (lb) atomicOr(&nonbin, 1);
  if (lf) atomicOr(&nonfloat, 1);
  __syncthreads();
  if (threadIdx.x == 0)
    mode_out[0] = (nonbin == 0) ? 0 : ((nonfloat == 0) ? 2 : 1);
}

// ============================ CSR build ============================
__global__ void k_count(const void* mask, const int* dst, int* cnt, const int* mode_p) {
  int e = blockIdx.x * 256 + threadIdx.x;
  if (e >= EE) return;
  if (mask_at(mask, e, *mode_p)) atomicAdd(&cnt[dst[e]], 1);
}

__global__ void k_scan_a(const int* cnt, int* blockSums) {
  __shared__ int sd[256];
  int t = threadIdx.x;
  int base = blockIdx.x * 1024 + t * 4;
  int s = 0;
  #pragma unroll
  for (int j = 0; j < 4; ++j) {
    int i = base + j;
    if (i < NN) s += cnt[i];
  }
  sd[t] = s;
  __syncthreads();
  for (int off = 128; off > 0; off >>= 1) {
    if (t < off) sd[t] += sd[t + off];
    __syncthreads();
  }
  if (t == 0) blockSums[blockIdx.x] = sd[0];
}

__global__ void k_scan_b(int* blockSums, int nb, int* total_out) {
  __shared__ int sd[128];
  int t = threadIdx.x;
  int v = (t < nb) ? blockSums[t] : 0;
  sd[t] = v;
  __syncthreads();
  for (int off = 1; off < 128; off <<= 1) {
    int x = (t >= off) ? sd[t - off] : 0;
    __syncthreads();
    sd[t] += x;
    __syncthreads();
  }
  if (t < nb) blockSums[t] = sd[t] - v;
  if (t == 0) total_out[0] = sd[127];
}

__global__ void k_scan_c(const int* cnt, const int* blockOffs, int* row_ptr,
                         int* cursor, float* cinv) {
  __shared__ int sd[256];
  int t = threadIdx.x;
  int base = blockIdx.x * 1024 + t * 4;
  int v[4], s = 0;
  #pragma unroll
  for (int j = 0; j < 4; ++j) {
    int i = base + j;
    v[j] = (i < NN) ? cnt[i] : 0;
    s += v[j];
  }
  sd[t] = s;
  __syncthreads();
  for (int off = 1; off < 256; off <<= 1) {
    int x = (t >= off) ? sd[t - off] : 0;
    __syncthreads();
    sd[t] += x;
    __syncthreads();
  }
  int excl = sd[t] - s + blockOffs[blockIdx.x];
  #pragma unroll
  for (int j = 0; j < 4; ++j) {
    int i = base + j;
    if (i < NN) {
      row_ptr[i] = excl;
      cursor[i] = excl;
      cinv[i] = 1.0f / fmaxf((float)v[j], 1.0f);
    }
    excl += v[j];
  }
}

__global__ void k_fill(const void* mask, const int* src, const int* dst,
                       int* cursor, int* col, const int* mode_p) {
  int e = blockIdx.x * 256 + threadIdx.x;
  if (e >= EE) return;
  if (mask_at(mask, e, *mode_p)) {
    int p = atomicAdd(&cursor[dst[e]], 1);
    col[p] = src[e];
  }
}

// ============================ folded / transposed weights (bf16) ============================
__global__ void k_prep(const float* msg_W, const float* msg_b, const float* upd_W,
                       const float* Wi, const float* Wf,
                       u16* Wu1T, u16* A1T, u16* A2T, float* C1,
                       u16* WiT, u16* WfT) {
  int t = threadIdx.x;
  if (blockIdx.x == 2) {
    for (int o = t; o < 4096; o += 256) {
      int k = o >> 6, n = o & 63;
      WiT[n * 64 + k] = (u16)f2bf(Wi[k * 64 + n]);
      WfT[n * 64 + k] = (u16)f2bf(Wf[k * 64 + n]);
    }
    return;
  }
  int l = blockIdx.x;
  const float* WmT = msg_W + l * 8192;
  const float* WmB = WmT + 4096;
  const float* Wu1 = upd_W + l * 8192;
  const float* Wu2 = Wu1 + 4096;
  for (int o = t; o < 4096; o += 256) {
    int a = o >> 6, b = o & 63;   // a = k-dim, b = n-dim
    float a1 = 0.f, a2 = 0.f;
    for (int j = 0; j < 64; ++j) {
      float w2 = Wu2[j * 64 + b];
      a1 = fmaf(WmT[a * 64 + j], w2, a1);
      a2 = fmaf(WmB[a * 64 + j], w2, a2);
    }
    A1T[l * 4096 + b * 64 + a]  = (u16)f2bf(a1);
    A2T[l * 4096 + b * 64 + a]  = (u16)f2bf(a2);
    Wu1T[l * 4096 + b * 64 + a] = (u16)f2bf(Wu1[a * 64 + b]);
  }
  if (t < 64) {
    float acc = 0.f;
    for (int j = 0; j < 64; ++j) acc = fmaf(msg_b[l * 64 + j], Wu2[j * 64 + t], acc);
    C1[l * 64 + t] = acc;
  }
}

// ============================ MFMA helpers ============================
// Wave w owns rows [w*16, w*16+16). A-frag: A[m=lane&15][k=quad*8+j].
// B-frag from padded LDS (R7 lesson: NEVER read B-operands from global —
// latency-exposed in the MFMA chain). C/D: col=lane&15, row=quad*4+reg.
__device__ __forceinline__ void mm4(const u16* lW, int m16, int q,
                                    bf16x8 a0, bf16x8 a1, f32x4 (&acc)[4]) {
  #pragma unroll
  for (int nt = 0; nt < 4; ++nt) {
    const u16* wp = lW + (nt * 16 + m16) * WSTR + q * 8;
    bf16x8 b0 = *(const bf16x8*)(wp);
    bf16x8 b1 = *(const bf16x8*)(wp + 32);
    acc[nt] = __builtin_amdgcn_mfma_f32_16x16x32_bf16(a0, b0, acc[nt], 0, 0, 0);
    acc[nt] = __builtin_amdgcn_mfma_f32_16x16x32_bf16(a1, b1, acc[nt], 0, 0, 0);
  }
}

// stage 64x64 bf16 weight (unpadded global) into padded LDS (stride WSTR)
__device__ __forceinline__ void stage_W(const u16* __restrict__ WT, u16* lW) {
  int t = threadIdx.x;
  int r = t >> 2, seg = (t & 3) * 16;
  const uint4* p = (const uint4*)(WT + r * 64 + seg);
  uint4 a = p[0], b = p[1];
  *(uint4*)(lW + r * WSTR + seg) = a;
  *(uint4*)(lW + r * WSTR + seg + 8) = b;
}

// stage 64-row bf16 H tile into padded LDS
__device__ __forceinline__ void stage_H(const u16* __restrict__ Hin, int R0, u16* lT) {
  int t = threadIdx.x;
  int r = t >> 2, seg = (t & 3) * 16;
  int gr = R0 + r;
  uint4 a = {0, 0, 0, 0}, b = {0, 0, 0, 0};
  if (gr < NN) {
    const uint4* p = (const uint4*)(Hin + (size_t)gr * 64 + seg);
    a = p[0]; b = p[1];
  }
  *(uint4*)(lT + r * WSTR + seg) = a;
  *(uint4*)(lT + r * WSTR + seg + 8) = b;
}

// ============================ input projection ============================
// H[inst] = relu((x + noise_inst) @ Wi + bi), bf16 out
__global__ __launch_bounds__(256) void k_input(const float* __restrict__ x,
                                               const u16* __restrict__ WiT,
                                               const float* __restrict__ bi,
                                               u16* __restrict__ HoutB) {
  __shared__ __align__(16) u16 lT[64 * WSTR];
  __shared__ __align__(16) u16 lW[64 * WSTR];
  __shared__ float lB[64];
  int t = threadIdx.x;
  int R0 = blockIdx.x * 64;
  int inst = blockIdx.y;
  u16* Hout = HoutB + (size_t)inst * SLAB;
  {
    int r = t >> 2, seg = (t & 3) * 16;
    int gr = R0 + r;
    float v[16];
    if (gr < NN) {
      const float4* xp = (const float4*)(x + (size_t)gr * 64 + seg);
      #pragma unroll
      for (int qq = 0; qq < 4; ++qq) {
        float4 f = xp[qq];
        v[qq * 4 + 0] = f.x; v[qq * 4 + 1] = f.y;
        v[qq * 4 + 2] = f.z; v[qq * 4 + 3] = f.w;
      }
      if (inst > 0) {
        int s = inst - 1;
        #pragma unroll
        for (int j = 0; j < 16; ++j) v[j] += noise_val(s, gr, seg + j);
      }
    } else {
      #pragma unroll
      for (int j = 0; j < 16; ++j) v[j] = 0.f;
    }
    uint32_t pk[8];
    #pragma unroll
    for (int j = 0; j < 8; ++j)
      pk[j] = f2bf(v[2 * j]) | (f2bf(v[2 * j + 1]) << 16);
    uint4 A = {pk[0], pk[1], pk[2], pk[3]};
    uint4 B = {pk[4], pk[5], pk[6], pk[7]};
    *(uint4*)(lT + r * WSTR + seg) = A;
    *(uint4*)(lT + r * WSTR + seg + 8) = B;
  }
  stage_W(WiT, lW);
  if (t < 64) lB[t] = bi[t];
  __syncthreads();
  int l = t & 63, w = t >> 6;
  int m16 = l & 15, q = l >> 4;
  const u16* aRow = lT + (w * 16 + m16) * WSTR + q * 8;
  bf16x8 fa0 = *(const bf16x8*)(aRow);
  bf16x8 fa1 = *(const bf16x8*)(aRow + 32);
  f32x4 acc[4] = {{0.f, 0.f, 0.f, 0.f}, {0.f, 0.f, 0.f, 0.f},
                  {0.f, 0.f, 0.f, 0.f}, {0.f, 0.f, 0.f, 0.f}};
  mm4(lW, m16, q, fa0, fa1, acc);
  #pragma unroll
  for (int nt = 0; nt < 4; ++nt) {
    int c = nt * 16 + m16;
    #pragma unroll
    for (int r_ = 0; r_ < 4; ++r_) {
      int row = w * 16 + q * 4 + r_;
      int gr = R0 + row;
      if (gr < NN) {
        float vv = fmaxf(acc[nt][r_] + lB[c], 0.f);
        Hout[(size_t)gr * 64 + c] = (u16)f2bf(vv);
      }
    }
  }
}

// ============================ fused gather + layer update (2 instances/block) ============================
// Hn = relu(H@Wu1 + g*(H@A1) + (cinv*gatherSum(H))@A2 + b0 + g*c1)
// R5's proven row-serial gather, but each block processes an INSTANCE PAIR:
// same edge list, two H slabs -> 8 independent loads in flight per inner
// iteration (2x the MLP of R5) and half the col/row_ptr traffic.
// Weights staged in LDS (R7 lesson); A-frags loaded from global BEFORE the
// gather (fully latency-hidden).
__global__ __launch_bounds__(256) void k_layer(const u16* __restrict__ HinB,
                                               u16* __restrict__ HoutB,
                                               const int* __restrict__ row_ptr,
                                               const int* __restrict__ col,
                                               const int* __restrict__ cnt,
                                               const float* __restrict__ cinv,
                                               const u16* __restrict__ Wu1T,
                                               const u16* __restrict__ A1T,
                                               const u16* __restrict__ A2T,
                                               const float* __restrict__ b0,
                                               const float* __restrict__ c1) {
  __shared__ __align__(16) u16 lS0[64 * WSTR];
  __shared__ __align__(16) u16 lS1[64 * WSTR];
  __shared__ __align__(16) u16 lW[64 * WSTR];
  __shared__ float lB[128];
  __shared__ float lG[64];
  int t = threadIdx.x;
  int R0 = blockIdx.x * 64;
  int instBase = blockIdx.y * 2;
  bool two = (instBase + 1) < 5;
  const u16* Hin0 = HinB + (size_t)instBase * SLAB;
  const u16* Hin1 = Hin0 + (two ? SLAB : 0);
  u16* Hout0 = HoutB + (size_t)instBase * SLAB;
  u16* Hout1 = Hout0 + SLAB;

  stage_W(Wu1T, lW);
  if (t < 64) {
    lB[t] = b0[t];
    lB[64 + t] = c1[t];
    int gr = R0 + t;
    lG[t] = (gr < NN && cnt[gr] > 0) ? 1.f : 0.f;
  }

  int l = t & 63, w = t >> 6;
  int m16 = l & 15, q = l >> 4;
  int arow = w * 16 + m16;
  int gra = R0 + arow;
  bf16x8 zz = {0, 0, 0, 0, 0, 0, 0, 0};
  bf16x8 fa0_0 = zz, fa1_0 = zz, fa0_1 = zz, fa1_1 = zz;
  if (gra < NN) {
    const u16* ap = Hin0 + (size_t)gra * 64 + q * 8;
    fa0_0 = *(const bf16x8*)(ap);
    fa1_0 = *(const bf16x8*)(ap + 32);
    if (two) {
      const u16* ap1 = Hin1 + (size_t)gra * 64 + q * 8;
      fa0_1 = *(const bf16x8*)(ap1);
      fa1_1 = *(const bf16x8*)(ap1 + 32);
    }
  }

  // gather bf16 neighbor rows: 16 lanes x 8 B per edge row, both instances
  {
    int wv = t >> 6, sub = (t >> 4) & 3, f0 = (t & 15) << 2;
    const u16* hb0 = Hin0 + f0;
    const u16* hb1 = Hin1 + f0;
    #pragma unroll
    for (int bb = 0; bb < 4; ++bb) {
      int r = wv * 16 + bb * 4 + sub;
      int n = R0 + r;
      float g0 = 0.f, g1 = 0.f, g2 = 0.f, g3 = 0.f;
      float h0 = 0.f, h1 = 0.f, h2 = 0.f, h3 = 0.f;
      if (n < NN) {
        int e = row_ptr[n], end = row_ptr[n + 1];
        for (; e + 4 <= end; e += 4) {
          size_t o0 = (size_t)col[e] * 64, o1 = (size_t)col[e + 1] * 64;
          size_t o2 = (size_t)col[e + 2] * 64, o3 = (size_t)col[e + 3] * 64;
          uint2 p0 = *(const uint2*)(hb0 + o0);
          uint2 p1 = *(const uint2*)(hb0 + o1);
          uint2 p2 = *(const uint2*)(hb0 + o2);
          uint2 p3 = *(const uint2*)(hb0 + o3);
          g0 += (__uint_as_float(p0.x << 16) + __uint_as_float(p1.x << 16)) +
                (__uint_as_float(p2.x << 16) + __uint_as_float(p3.x << 16));
          g1 += (__uint_as_float(p0.x & 0xffff0000u) + __uint_as_float(p1.x & 0xffff0000u)) +
                (__uint_as_float(p2.x & 0xffff0000u) + __uint_as_float(p3.x & 0xffff0000u));
          g2 += (__uint_as_float(p0.y << 16) + __uint_as_float(p1.y << 16)) +
                (__uint_as_float(p2.y << 16) + __uint_as_float(p3.y << 16));
          g3 += (__uint_as_float(p0.y & 0xffff0000u) + __uint_as_float(p1.y & 0xffff0000u)) +
                (__uint_as_float(p2.y & 0xffff0000u) + __uint_as_float(p3.y & 0xffff0000u));
          if (two) {
            uint2 q0 = *(const uint2*)(hb1 + o0);
            uint2 q1 = *(const uint2*)(hb1 + o1);
            uint2 q2 = *(const uint2*)(hb1 + o2);
            uint2 q3 = *(const uint2*)(hb1 + o3);
            h0 += (__uint_as_float(q0.x << 16) + __uint_as_float(q1.x << 16)) +
                  (__uint_as_float(q2.x << 16) + __uint_as_float(q3.x << 16));
            h1 += (__uint_as_float(q0.x & 0xffff0000u) + __uint_as_float(q1.x & 0xffff0000u)) +
                  (__uint_as_float(q2.x & 0xffff0000u) + __uint_as_float(q3.x & 0xffff0000u));
            h2 += (__uint_as_float(q0.y << 16) + __uint_as_float(q1.y << 16)) +
                  (__uint_as_float(q2.y << 16) + __uint_as_float(q3.y << 16));
            h3 += (__uint_as_float(q0.y & 0xffff0000u) + __uint_as_float(q1.y & 0xffff0000u)) +
                  (__uint_as_float(q2.y & 0xffff0000u) + __uint_as_float(q3.y & 0xffff0000u));
          }
        }
        for (; e < end; ++e) {
          size_t o0 = (size_t)col[e] * 64;
          uint2 p0 = *(const uint2*)(hb0 + o0);
          g0 += __uint_as_float(p0.x << 16);
          g1 += __uint_as_float(p0.x & 0xffff0000u);
          g2 += __uint_as_float(p0.y << 16);
          g3 += __uint_as_float(p0.y & 0xffff0000u);
          if (two) {
            uint2 q0 = *(const uint2*)(hb1 + o0);
            h0 += __uint_as_float(q0.x << 16);
            h1 += __uint_as_float(q0.x & 0xffff0000u);
            h2 += __uint_as_float(q0.y << 16);
            h3 += __uint_as_float(q0.y & 0xffff0000u);
          }
        }
        float ci = cinv[n];
        g0 *= ci; g1 *= ci; g2 *= ci; g3 *= ci;
        h0 *= ci; h1 *= ci; h2 *= ci; h3 *= ci;
      }
      uint2 pk;
      pk.x = f2bf(g0) | (f2bf(g1) << 16);
      pk.y = f2bf(g2) | (f2bf(g3) << 16);
      *(uint2*)(lS0 + r * WSTR + f0) = pk;
      if (two) {
        uint2 pk2;
        pk2.x = f2bf(h0) | (f2bf(h1) << 16);
        pk2.y = f2bf(h2) | (f2bf(h3) << 16);
        *(uint2*)(lS1 + r * WSTR + f0) = pk2;
      }
    }
  }
  __syncthreads();

  float gA = lG[arow];
  f32x4 acc0[4] = {{0.f, 0.f, 0.f, 0.f}, {0.f, 0.f, 0.f, 0.f},
                   {0.f, 0.f, 0.f, 0.f}, {0.f, 0.f, 0.f, 0.f}};
  f32x4 acc1[4] = {{0.f, 0.f, 0.f, 0.f}, {0.f, 0.f, 0.f, 0.f},
                   {0.f, 0.f, 0.f, 0.f}, {0.f, 0.f, 0.f, 0.f}};
  mm4(lW, m16, q, fa0_0, fa1_0, acc0);            // H @ Wu1
  if (two) mm4(lW, m16, q, fa0_1, fa1_1, acc1);
  __syncthreads();
  stage_W(A1T, lW);
  __syncthreads();
  {
    bf16x8 ga0 = (gA != 0.f) ? fa0_0 : zz;
    bf16x8 ga1 = (gA != 0.f) ? fa1_0 : zz;
    mm4(lW, m16, q, ga0, ga1, acc0);              // g * (H @ A1)
    if (two) {
      bf16x8 gb0 = (gA != 0.f) ? fa0_1 : zz;
      bf16x8 gb1 = (gA != 0.f) ? fa1_1 : zz;
      mm4(lW, m16, q, gb0, gb1, acc1);
    }
  }
  __syncthreads();
  stage_W(A2T, lW);
  __syncthreads();
  {
    const u16* sRow = lS0 + arow * WSTR + q * 8;
    bf16x8 fs0 = *(const bf16x8*)(sRow);
    bf16x8 fs1 = *(const bf16x8*)(sRow + 32);
    mm4(lW, m16, q, fs0, fs1, acc0);              // (cinv*S) @ A2
    if (two) {
      const u16* sRow1 = lS1 + arow * WSTR + q * 8;
      bf16x8 ft0 = *(const bf16x8*)(sRow1);
      bf16x8 ft1 = *(const bf16x8*)(sRow1 + 32);
      mm4(lW, m16, q, ft0, ft1, acc1);
    }
  }
  #pragma unroll
  for (int nt = 0; nt < 4; ++nt) {
    int c = nt * 16 + m16;
    #pragma unroll
    for (int r_ = 0; r_ < 4; ++r_) {
      int row = w * 16 + q * 4 + r_;
      int gr = R0 + row;
      if (gr < NN) {
        float bias = lB[c] + lG[row] * lB[64 + c];
        float v0 = fmaxf(acc0[nt][r_] + bias, 0.f);
        Hout0[(size_t)gr * 64 + c] = (u16)f2bf(v0);
        if (two) {
          float v1 = fmaxf(acc1[nt][r_] + bias, 0.f);
          Hout1[(size_t)gr * 64 + c] = (u16)f2bf(v1);
        }
      }
    }
  }
}

// ============================ final projection + variance (fused) ============================
__global__ __launch_bounds__(256) void k_final(const u16* __restrict__ HinB,
                                               const u16* __restrict__ WfT,
                                               const float* __restrict__ bfv,
                                               float* __restrict__ outCausal,
                                               float* __restrict__ out_u) {
  __shared__ __align__(16) u16 lT[64 * WSTR];
  __shared__ __align__(16) u16 lW[64 * WSTR];
  __shared__ float lB[64];
  int t = threadIdx.x;
  int R0 = blockIdx.x * 64;
  stage_W(WfT, lW);
  if (t < 64) lB[t] = bfv[t];
  int l = t & 63, w = t >> 6;
  int m16 = l & 15, q = l >> 4;
  float s1[16], s2[16];
  #pragma unroll
  for (int j = 0; j < 16; ++j) { s1[j] = 0.f; s2[j] = 0.f; }

  for (int inst = 0; inst < 5; ++inst) {
    __syncthreads();
    stage_H(HinB + (size_t)inst * SLAB, R0, lT);
    __syncthreads();
    const u16* aRow = lT + (w * 16 + m16) * WSTR + q * 8;
    bf16x8 fa0 = *(const bf16x8*)(aRow);
    bf16x8 fa1 = *(const bf16x8*)(aRow + 32);
    f32x4 acc[4] = {{0.f, 0.f, 0.f, 0.f}, {0.f, 0.f, 0.f, 0.f},
                    {0.f, 0.f, 0.f, 0.f}, {0.f, 0.f, 0.f, 0.f}};
    mm4(lW, m16, q, fa0, fa1, acc);
    #pragma unroll
    for (int nt = 0; nt < 4; ++nt) {
      int c = nt * 16 + m16;
      #pragma unroll
      for (int r_ = 0; r_ < 4; ++r_) {
        float z = acc[nt][r_] + lB[c];
        if (inst == 0) {
          int gr = R0 + w * 16 + q * 4 + r_;
          if (gr < NN) outCausal[(size_t)gr * 64 + c] = z;
        } else {
          s1[nt * 4 + r_] += z;
          s2[nt * 4 + r_] = fmaf(z, z, s2[nt * 4 + r_]);
        }
      }
    }
  }
  #pragma unroll
  for (int r_ = 0; r_ < 4; ++r_) {
    float pr = 0.f;
    #pragma unroll
    for (int nt = 0; nt < 4; ++nt) {
      float a = s1[nt * 4 + r_];
      pr += s2[nt * 4 + r_] - 0.25f * a * a;
    }
    #pragma unroll
    for (int msk = 1; msk < 16; msk <<= 1)
      pr += __shfl_xor(pr, msk, 64);
    if (m16 == 0) {
      int gr = R0 + w * 16 + q * 4 + r_;
      if (gr < NN) out_u[gr] = fmaxf(pr * (1.0f / 3.0f), 1e-6f);
    }
  }
}

// ============================ launch ============================
extern "C" void kernel_launch(void* const* d_in, const int* in_sizes, int n_in,
                              void* d_out, int out_size, void* d_ws, size_t ws_size,
                              hipStream_t stream) {
  const float* x      = (const float*)d_in[0];
  const int*   eidx   = (const int*)d_in[1];
  const void*  mask   = d_in[2];
  const float* Wi     = (const float*)d_in[3];
  const float* bi     = (const float*)d_in[4];
  const float* msg_W  = (const float*)d_in[5];
  const float* msg_b  = (const float*)d_in[6];
  const float* upd_W  = (const float*)d_in[7];
  const float* upd_b  = (const float*)d_in[8];
  const float* Wf     = (const float*)d_in[9];
  const float* bfv    = (const float*)d_in[10];

  const int* src = eidx;
  const int* dst = eidx + EE;

  char* ws = (char*)d_ws;
  size_t off = 0;
  auto alloc = [&](size_t bytes) -> void* {
    void* p = ws + off;
    off += (bytes + 255) & ~(size_t)255;
    return p;
  };

  int*   cnt     = (int*)alloc(NN * sizeof(int));
  float* cinv    = (float*)alloc(NN * sizeof(float));
  int*   row_ptr = (int*)alloc((NN + 1) * sizeof(int));
  int*   cursor  = (int*)alloc(NN * sizeof(int));
  int*   col     = (int*)alloc(EE * sizeof(int));
  int*   bsums   = (int*)alloc(128 * sizeof(int));
  int*   mode_p  = (int*)alloc(sizeof(int));
  u16*   Wu1T    = (u16*)alloc(2 * 4096 * sizeof(u16));
  u16*   A1T     = (u16*)alloc(2 * 4096 * sizeof(u16));
  u16*   A2T     = (u16*)alloc(2 * 4096 * sizeof(u16));
  u16*   WiT     = (u16*)alloc(4096 * sizeof(u16));
  u16*   WfT     = (u16*)alloc(4096 * sizeof(u16));
  float* C1      = (float*)alloc(2 * 64 * sizeof(float));
  u16*   HA      = (u16*)alloc(5 * SLAB * sizeof(u16));   // 64 MB
  u16*   HB      = (u16*)alloc(5 * SLAB * sizeof(u16));   // 64 MB

  float* out_causal = (float*)d_out;
  float* out_u      = (float*)d_out + SLAB;

  // ---- CSR build ----
  k_detect<<<1, 256, 0, stream>>>((const unsigned*)mask, mode_p);
  hipMemsetAsync(cnt, 0, NN * sizeof(int), stream);
  k_count<<<EE / 256, 256, 0, stream>>>(mask, dst, cnt, mode_p);
  const int SCAN_BLKS = (NN + 1023) / 1024;  // 98
  k_scan_a<<<SCAN_BLKS, 256, 0, stream>>>(cnt, bsums);
  k_scan_b<<<1, 128, 0, stream>>>(bsums, SCAN_BLKS, row_ptr + NN);
  k_scan_c<<<SCAN_BLKS, 256, 0, stream>>>(cnt, bsums, row_ptr, cursor, cinv);
  k_fill<<<EE / 256, 256, 0, stream>>>(mask, src, dst, cursor, col, mode_p);

  // ---- weights ----
  k_prep<<<3, 256, 0, stream>>>(msg_W, msg_b, upd_W, Wi, Wf,
                                Wu1T, A1T, A2T, C1, WiT, WfT);

  // ---- 5 batched GNN passes ----
  dim3 g5(GEMM_BX, 5);
  dim3 gl(GEMM_BX, 3);   // instance pairs {0,1},{2,3},{4}
  k_input<<<g5, 256, 0, stream>>>(x, WiT, bi, HA);
  k_layer<<<gl, 256, 0, stream>>>(HA, HB, row_ptr, col, cnt, cinv,
                                  Wu1T, A1T, A2T, upd_b, C1);
  k_layer<<<gl, 256, 0, stream>>>(HB, HA, row_ptr, col, cnt, cinv,
                                  Wu1T + 4096, A1T + 4096, A2T + 4096,
                                  upd_b + 64, C1 + 64);
  k_final<<<GEMM_BX, 256, 0, stream>>>(HA, WfT, bfv, out_causal, out_u);

  (void)in_sizes; (void)n_in; (void)out_size; (void)ws_size;
}

// Round 9
// 503.310 us; speedup vs baseline: 4.3128x; 1.0474x over previous
//
#include <hip/hip_runtime.h>
#include <stdint.h>

#define NN 100000
#define EE 800000
#define GEMM_BX 1563          // ceil(100000/64)
#define WSTR 72               // padded bf16 LDS row stride (144 B: 2-way bank aliasing = free)
#define SLAB ((size_t)NN * 64)

typedef unsigned short u16;
typedef __attribute__((ext_vector_type(8))) short bf16x8;   // 8 bf16 = 4 VGPRs
typedef __attribute__((ext_vector_type(4))) float f32x4;

// f32 -> bf16 RNE
__device__ __forceinline__ uint32_t f2bf(float f) {
  uint32_t u = __float_as_uint(f);
  return (u + 0x7fffu + ((u >> 16) & 1u)) >> 16;
}

// ============================ threefry / noise ============================
__device__ __forceinline__ void tf_round(uint32_t& x0, uint32_t& x1, int r) {
  x0 += x1;
  x1 = (x1 << r) | (x1 >> (32 - r));
  x1 ^= x0;
}

// threefry2x32 with key (0, 42) == jax.random.key(42)
__device__ __forceinline__ void threefry_0_42(uint32_t c0, uint32_t c1,
                                              uint32_t& o0, uint32_t& o1) {
  const uint32_t ks0 = 0u, ks1 = 42u, ks2 = 0x1BD11BDAu ^ 42u;
  uint32_t x0 = c0 + ks0, x1 = c1 + ks1;
  tf_round(x0, x1, 13); tf_round(x0, x1, 15); tf_round(x0, x1, 26); tf_round(x0, x1, 6);
  x0 += ks1; x1 += ks2 + 1u;
  tf_round(x0, x1, 17); tf_round(x0, x1, 29); tf_round(x0, x1, 16); tf_round(x0, x1, 24);
  x0 += ks2; x1 += ks0 + 2u;
  tf_round(x0, x1, 13); tf_round(x0, x1, 15); tf_round(x0, x1, 26); tf_round(x0, x1, 6);
  x0 += ks0; x1 += ks1 + 3u;
  tf_round(x0, x1, 17); tf_round(x0, x1, 29); tf_round(x0, x1, 16); tf_round(x0, x1, 24);
  x0 += ks1; x1 += ks2 + 4u;
  tf_round(x0, x1, 13); tf_round(x0, x1, 15); tf_round(x0, x1, 26); tf_round(x0, x1, 6);
  x0 += ks2; x1 += ks0 + 5u;
  o0 = x0; o1 = x1;
}

// jax_threefry_partitionable noise (verified R2): bits = o0^o1 of threefry((0,42),(0,f))
__device__ __forceinline__ float noise_val(int s, int n, int d) {
  uint32_t f = (uint32_t)s * 6400000u + (uint32_t)n * 64u + (uint32_t)d;
  uint32_t o0, o1;
  threefry_0_42(0u, f, o0, o1);
  uint32_t bits = o0 ^ o1;
  float v = __uint_as_float((bits >> 9) | 0x3f800000u) - 1.0f;
  const float LO = -0.99999994f;
  float u = v * 2.0f + LO;
  u = fmaxf(u, LO);
  float w = -__logf(fmaf(-u, u, 1.0f));
  float ww = w - 2.5f;
  float p = 2.81022636e-08f;
  p = fmaf(p, ww, 3.43273939e-07f);
  p = fmaf(p, ww, -3.5233877e-06f);
  p = fmaf(p, ww, -4.39150654e-06f);
  p = fmaf(p, ww, 0.00021858087f);
  p = fmaf(p, ww, -0.00125372503f);
  p = fmaf(p, ww, -0.00417768164f);
  p = fmaf(p, ww, 0.246640727f);
  p = fmaf(p, ww, 1.50140941f);
  if (__any(w >= 5.0f)) {
    float ws = sqrtf(w) - 3.0f;
    float p2 = -0.000200214257f;
    p2 = fmaf(p2, ws, 0.000100950558f);
    p2 = fmaf(p2, ws, 0.00134934322f);
    p2 = fmaf(p2, ws, -0.00367342844f);
    p2 = fmaf(p2, ws, 0.00573950773f);
    p2 = fmaf(p2, ws, -0.0076224613f);
    p2 = fmaf(p2, ws, 0.00943887047f);
    p2 = fmaf(p2, ws, 1.00167406f);
    p2 = fmaf(p2, ws, 2.83297682f);
    p = (w < 5.0f) ? p : p2;
  }
  return 0.141421356f * (p * u);   // 0.1 * sqrt(2) * erfinv(u)
}

// ============================ mask dtype detection ============================
__device__ __forceinline__ int mask_at(const void* m, int e, int mode) {
  if (mode == 0) return ((const int*)m)[e] != 0;
  if (mode == 1) return ((const unsigned char*)m)[e] != 0;
  return ((const float*)m)[e] != 0.0f;
}

__global__ void k_detect(const unsigned* mw, int* mode_out) {
  __shared__ int nonbin, nonfloat;
  if (threadIdx.x == 0) { nonbin = 0; nonfloat = 0; }
  __syncthreads();
  int lb = 0, lf = 0;
  for (int i = threadIdx.x; i < 4096; i += 256) {
    unsigned v = mw[i];
    if (v > 1u) lb = 1;
    if (v != 0u && v != 0x3F800000u) lf = 1;
  }
  if (lb) atomicOr(&nonbin, 1);
  if (lf) atomicOr(&nonfloat, 1);
  __syncthreads();
  if (threadIdx.x == 0)
    mode_out[0] = (nonbin == 0) ? 0 : ((nonfloat == 0) ? 2 : 1);
}

// ============================ CSR build ============================
__global__ void k_count(const void* mask, const int* dst, int* cnt, const int* mode_p) {
  int e = blockIdx.x * 256 + threadIdx.x;
  if (e >= EE) return;
  if (mask_at(mask, e, *mode_p)) atomicAdd(&cnt[dst[e]], 1);
}

__global__ void k_scan_a(const int* cnt, int* blockSums) {
  __shared__ int sd[256];
  int t = threadIdx.x;
  int base = blockIdx.x * 1024 + t * 4;
  int s = 0;
  #pragma unroll
  for (int j = 0; j < 4; ++j) {
    int i = base + j;
    if (i < NN) s += cnt[i];
  }
  sd[t] = s;
  __syncthreads();
  for (int off = 128; off > 0; off >>= 1) {
    if (t < off) sd[t] += sd[t + off];
    __syncthreads();
  }
  if (t == 0) blockSums[blockIdx.x] = sd[0];
}

__global__ void k_scan_b(int* blockSums, int nb, int* total_out) {
  __shared__ int sd[128];
  int t = threadIdx.x;
  int v = (t < nb) ? blockSums[t] : 0;
  sd[t] = v;
  __syncthreads();
  for (int off = 1; off < 128; off <<= 1) {
    int x = (t >= off) ? sd[t - off] : 0;
    __syncthreads();
    sd[t] += x;
    __syncthreads();
  }
  if (t < nb) blockSums[t] = sd[t] - v;
  if (t == 0) total_out[0] = sd[127];
}

__global__ void k_scan_c(const int* cnt, const int* blockOffs, int* row_ptr,
                         int* cursor, float* cinv) {
  __shared__ int sd[256];
  int t = threadIdx.x;
  int base = blockIdx.x * 1024 + t * 4;
  int v[4], s = 0;
  #pragma unroll
  for (int j = 0; j < 4; ++j) {
    int i = base + j;
    v[j] = (i < NN) ? cnt[i] : 0;
    s += v[j];
  }
  sd[t] = s;
  __syncthreads();
  for (int off = 1; off < 256; off <<= 1) {
    int x = (t >= off) ? sd[t - off] : 0;
    __syncthreads();
    sd[t] += x;
    __syncthreads();
  }
  int excl = sd[t] - s + blockOffs[blockIdx.x];
  #pragma unroll
  for (int j = 0; j < 4; ++j) {
    int i = base + j;
    if (i < NN) {
      row_ptr[i] = excl;
      cursor[i] = excl;
      cinv[i] = 1.0f / fmaxf((float)v[j], 1.0f);
    }
    excl += v[j];
  }
}

__global__ void k_fill(const void* mask, const int* src, const int* dst,
                       int* cursor, int* col, const int* mode_p) {
  int e = blockIdx.x * 256 + threadIdx.x;
  if (e >= EE) return;
  if (mask_at(mask, e, *mode_p)) {
    int p = atomicAdd(&cursor[dst[e]], 1);
    col[p] = src[e];
  }
}

// ============================ folded / transposed weights (bf16) ============================
__global__ void k_prep(const float* msg_W, const float* msg_b, const float* upd_W,
                       const float* Wi, const float* Wf,
                       u16* Wu1T, u16* A1T, u16* A2T, float* C1,
                       u16* WiT, u16* WfT) {
  int t = threadIdx.x;
  if (blockIdx.x == 2) {
    for (int o = t; o < 4096; o += 256) {
      int k = o >> 6, n = o & 63;
      WiT[n * 64 + k] = (u16)f2bf(Wi[k * 64 + n]);
      WfT[n * 64 + k] = (u16)f2bf(Wf[k * 64 + n]);
    }
    return;
  }
  int l = blockIdx.x;
  const float* WmT = msg_W + l * 8192;
  const float* WmB = WmT + 4096;
  const float* Wu1 = upd_W + l * 8192;
  const float* Wu2 = Wu1 + 4096;
  for (int o = t; o < 4096; o += 256) {
    int a = o >> 6, b = o & 63;   // a = k-dim, b = n-dim
    float a1 = 0.f, a2 = 0.f;
    for (int j = 0; j < 64; ++j) {
      float w2 = Wu2[j * 64 + b];
      a1 = fmaf(WmT[a * 64 + j], w2, a1);
      a2 = fmaf(WmB[a * 64 + j], w2, a2);
    }
    A1T[l * 4096 + b * 64 + a]  = (u16)f2bf(a1);
    A2T[l * 4096 + b * 64 + a]  = (u16)f2bf(a2);
    Wu1T[l * 4096 + b * 64 + a] = (u16)f2bf(Wu1[a * 64 + b]);
  }
  if (t < 64) {
    float acc = 0.f;
    for (int j = 0; j < 64; ++j) acc = fmaf(msg_b[l * 64 + j], Wu2[j * 64 + t], acc);
    C1[l * 64 + t] = acc;
  }
}

// ============================ MFMA helpers ============================
// Wave w owns rows [w*16, w*16+16). A-frag: A[m=lane&15][k=quad*8+j].
// B-frag from padded LDS (R7 lesson: NEVER read B-operands from global —
// latency-exposed in the MFMA chain). C/D: col=lane&15, row=quad*4+reg.
__device__ __forceinline__ void mm4(const u16* lW, int m16, int q,
                                    bf16x8 a0, bf16x8 a1, f32x4 (&acc)[4]) {
  #pragma unroll
  for (int nt = 0; nt < 4; ++nt) {
    const u16* wp = lW + (nt * 16 + m16) * WSTR + q * 8;
    bf16x8 b0 = *(const bf16x8*)(wp);
    bf16x8 b1 = *(const bf16x8*)(wp + 32);
    acc[nt] = __builtin_amdgcn_mfma_f32_16x16x32_bf16(a0, b0, acc[nt], 0, 0, 0);
    acc[nt] = __builtin_amdgcn_mfma_f32_16x16x32_bf16(a1, b1, acc[nt], 0, 0, 0);
  }
}

// stage 64x64 bf16 weight (unpadded global) into padded LDS (stride WSTR)
__device__ __forceinline__ void stage_W(const u16* __restrict__ WT, u16* lW) {
  int t = threadIdx.x;
  int r = t >> 2, seg = (t & 3) * 16;
  const uint4* p = (const uint4*)(WT + r * 64 + seg);
  uint4 a = p[0], b = p[1];
  *(uint4*)(lW + r * WSTR + seg) = a;
  *(uint4*)(lW + r * WSTR + seg + 8) = b;
}

// stage 64-row bf16 H tile into padded LDS
__device__ __forceinline__ void stage_H(const u16* __restrict__ Hin, int R0, u16* lT) {
  int t = threadIdx.x;
  int r = t >> 2, seg = (t & 3) * 16;
  int gr = R0 + r;
  uint4 a = {0, 0, 0, 0}, b = {0, 0, 0, 0};
  if (gr < NN) {
    const uint4* p = (const uint4*)(Hin + (size_t)gr * 64 + seg);
    a = p[0]; b = p[1];
  }
  *(uint4*)(lT + r * WSTR + seg) = a;
  *(uint4*)(lT + r * WSTR + seg + 8) = b;
}

// ============================ input projection ============================
// H[inst] = relu((x + noise_inst) @ Wi + bi), bf16 out
__global__ __launch_bounds__(256) void k_input(const float* __restrict__ x,
                                               const u16* __restrict__ WiT,
                                               const float* __restrict__ bi,
                                               u16* __restrict__ HoutB) {
  __shared__ __align__(16) u16 lT[64 * WSTR];
  __shared__ __align__(16) u16 lW[64 * WSTR];
  __shared__ float lB[64];
  int t = threadIdx.x;
  int R0 = blockIdx.x * 64;
  int inst = blockIdx.y;
  u16* Hout = HoutB + (size_t)inst * SLAB;
  {
    int r = t >> 2, seg = (t & 3) * 16;
    int gr = R0 + r;
    float v[16];
    if (gr < NN) {
      const float4* xp = (const float4*)(x + (size_t)gr * 64 + seg);
      #pragma unroll
      for (int qq = 0; qq < 4; ++qq) {
        float4 f = xp[qq];
        v[qq * 4 + 0] = f.x; v[qq * 4 + 1] = f.y;
        v[qq * 4 + 2] = f.z; v[qq * 4 + 3] = f.w;
      }
      if (inst > 0) {
        int s = inst - 1;
        #pragma unroll
        for (int j = 0; j < 16; ++j) v[j] += noise_val(s, gr, seg + j);
      }
    } else {
      #pragma unroll
      for (int j = 0; j < 16; ++j) v[j] = 0.f;
    }
    uint32_t pk[8];
    #pragma unroll
    for (int j = 0; j < 8; ++j)
      pk[j] = f2bf(v[2 * j]) | (f2bf(v[2 * j + 1]) << 16);
    uint4 A = {pk[0], pk[1], pk[2], pk[3]};
    uint4 B = {pk[4], pk[5], pk[6], pk[7]};
    *(uint4*)(lT + r * WSTR + seg) = A;
    *(uint4*)(lT + r * WSTR + seg + 8) = B;
  }
  stage_W(WiT, lW);
  if (t < 64) lB[t] = bi[t];
  __syncthreads();
  int l = t & 63, w = t >> 6;
  int m16 = l & 15, q = l >> 4;
  const u16* aRow = lT + (w * 16 + m16) * WSTR + q * 8;
  bf16x8 fa0 = *(const bf16x8*)(aRow);
  bf16x8 fa1 = *(const bf16x8*)(aRow + 32);
  f32x4 acc[4] = {{0.f, 0.f, 0.f, 0.f}, {0.f, 0.f, 0.f, 0.f},
                  {0.f, 0.f, 0.f, 0.f}, {0.f, 0.f, 0.f, 0.f}};
  mm4(lW, m16, q, fa0, fa1, acc);
  #pragma unroll
  for (int nt = 0; nt < 4; ++nt) {
    int c = nt * 16 + m16;
    #pragma unroll
    for (int r_ = 0; r_ < 4; ++r_) {
      int row = w * 16 + q * 4 + r_;
      int gr = R0 + row;
      if (gr < NN) {
        float vv = fmaxf(acc[nt][r_] + lB[c], 0.f);
        Hout[(size_t)gr * 64 + c] = (u16)f2bf(vv);
      }
    }
  }
}

// ============================ fused gather + layer update (2 instances/block) ============================
// Hn = relu(H@Wu1 + g*(H@A1) + (cinv*gatherSum(H))@A2 + b0 + g*c1)
// Gather: CLAMPED 8-WIDE batches (index min(e+j,end-1), invalid loads masked
// to zero after landing) — no serial remainder loop; most rows (<=8 edges,
// 73%) are exactly ONE col-load wave + ONE H-load wave. Instance pair shares
// the col indices (16 H loads in flight per iteration).
__global__ __launch_bounds__(256) void k_layer(const u16* __restrict__ HinB,
                                               u16* __restrict__ HoutB,
                                               const int* __restrict__ row_ptr,
                                               const int* __restrict__ col,
                                               const int* __restrict__ cnt,
                                               const float* __restrict__ cinv,
                                               const u16* __restrict__ Wu1T,
                                               const u16* __restrict__ A1T,
                                               const u16* __restrict__ A2T,
                                               const float* __restrict__ b0,
                                               const float* __restrict__ c1) {
  __shared__ __align__(16) u16 lS0[64 * WSTR];
  __shared__ __align__(16) u16 lS1[64 * WSTR];
  __shared__ __align__(16) u16 lW[64 * WSTR];
  __shared__ float lB[128];
  __shared__ float lG[64];
  int t = threadIdx.x;
  int R0 = blockIdx.x * 64;
  int instBase = blockIdx.y * 2;
  bool two = (instBase + 1) < 5;
  const u16* Hin0 = HinB + (size_t)instBase * SLAB;
  const u16* Hin1 = Hin0 + (two ? SLAB : 0);
  u16* Hout0 = HoutB + (size_t)instBase * SLAB;
  u16* Hout1 = Hout0 + SLAB;

  stage_W(Wu1T, lW);
  if (t < 64) {
    lB[t] = b0[t];
    lB[64 + t] = c1[t];
    int gr = R0 + t;
    lG[t] = (gr < NN && cnt[gr] > 0) ? 1.f : 0.f;
  }

  int l = t & 63, w = t >> 6;
  int m16 = l & 15, q = l >> 4;
  int arow = w * 16 + m16;
  int gra = R0 + arow;
  bf16x8 zz = {0, 0, 0, 0, 0, 0, 0, 0};
  bf16x8 fa0_0 = zz, fa1_0 = zz, fa0_1 = zz, fa1_1 = zz;
  if (gra < NN) {
    const u16* ap = Hin0 + (size_t)gra * 64 + q * 8;
    fa0_0 = *(const bf16x8*)(ap);
    fa1_0 = *(const bf16x8*)(ap + 32);
    if (two) {
      const u16* ap1 = Hin1 + (size_t)gra * 64 + q * 8;
      fa0_1 = *(const bf16x8*)(ap1);
      fa1_1 = *(const bf16x8*)(ap1 + 32);
    }
  }

  // gather bf16 neighbor rows: 16 lanes x 8 B per edge row, both instances,
  // clamped 8-wide batches
  {
    int wv = t >> 6, sub = (t >> 4) & 3, f0 = (t & 15) << 2;
    const u16* hb0 = Hin0 + f0;
    const u16* hb1 = Hin1 + f0;
    #pragma unroll
    for (int bb = 0; bb < 4; ++bb) {
      int r = wv * 16 + bb * 4 + sub;
      int n = R0 + r;
      float g0 = 0.f, g1 = 0.f, g2 = 0.f, g3 = 0.f;
      float h0 = 0.f, h1 = 0.f, h2 = 0.f, h3 = 0.f;
      if (n < NN) {
        int e = row_ptr[n], end = row_ptr[n + 1];
        for (; e < end; e += 8) {
          int last = end - 1;
          size_t offv[8];
          #pragma unroll
          for (int j = 0; j < 8; ++j) {
            int ee = e + j;
            ee = (ee < last) ? ee : last;
            offv[j] = (size_t)col[ee] * 64;
          }
          uint2 P[8];
          #pragma unroll
          for (int j = 0; j < 8; ++j) P[j] = *(const uint2*)(hb0 + offv[j]);
          uint2 Q[8];
          if (two) {
            #pragma unroll
            for (int j = 0; j < 8; ++j) Q[j] = *(const uint2*)(hb1 + offv[j]);
          }
          #pragma unroll
          for (int j = 1; j < 8; ++j) {
            bool ok = (e + j) < end;
            P[j].x = ok ? P[j].x : 0u;
            P[j].y = ok ? P[j].y : 0u;
            if (two) {
              Q[j].x = ok ? Q[j].x : 0u;
              Q[j].y = ok ? Q[j].y : 0u;
            }
          }
          #pragma unroll
          for (int j = 0; j < 8; ++j) {
            g0 += __uint_as_float(P[j].x << 16);
            g1 += __uint_as_float(P[j].x & 0xffff0000u);
            g2 += __uint_as_float(P[j].y << 16);
            g3 += __uint_as_float(P[j].y & 0xffff0000u);
          }
          if (two) {
            #pragma unroll
            for (int j = 0; j < 8; ++j) {
              h0 += __uint_as_float(Q[j].x << 16);
              h1 += __uint_as_float(Q[j].x & 0xffff0000u);
              h2 += __uint_as_float(Q[j].y << 16);
              h3 += __uint_as_float(Q[j].y & 0xffff0000u);
            }
          }
        }
        float ci = cinv[n];
        g0 *= ci; g1 *= ci; g2 *= ci; g3 *= ci;
        h0 *= ci; h1 *= ci; h2 *= ci; h3 *= ci;
      }
      uint2 pk;
      pk.x = f2bf(g0) | (f2bf(g1) << 16);
      pk.y = f2bf(g2) | (f2bf(g3) << 16);
      *(uint2*)(lS0 + r * WSTR + f0) = pk;
      if (two) {
        uint2 pk2;
        pk2.x = f2bf(h0) | (f2bf(h1) << 16);
        pk2.y = f2bf(h2) | (f2bf(h3) << 16);
        *(uint2*)(lS1 + r * WSTR + f0) = pk2;
      }
    }
  }
  __syncthreads();

  float gA = lG[arow];
  f32x4 acc0[4] = {{0.f, 0.f, 0.f, 0.f}, {0.f, 0.f, 0.f, 0.f},
                   {0.f, 0.f, 0.f, 0.f}, {0.f, 0.f, 0.f, 0.f}};
  f32x4 acc1[4] = {{0.f, 0.f, 0.f, 0.f}, {0.f, 0.f, 0.f, 0.f},
                   {0.f, 0.f, 0.f, 0.f}, {0.f, 0.f, 0.f, 0.f}};
  mm4(lW, m16, q, fa0_0, fa1_0, acc0);            // H @ Wu1
  if (two) mm4(lW, m16, q, fa0_1, fa1_1, acc1);
  __syncthreads();
  stage_W(A1T, lW);
  __syncthreads();
  {
    bf16x8 ga0 = (gA != 0.f) ? fa0_0 : zz;
    bf16x8 ga1 = (gA != 0.f) ? fa1_0 : zz;
    mm4(lW, m16, q, ga0, ga1, acc0);              // g * (H @ A1)
    if (two) {
      bf16x8 gb0 = (gA != 0.f) ? fa0_1 : zz;
      bf16x8 gb1 = (gA != 0.f) ? fa1_1 : zz;
      mm4(lW, m16, q, gb0, gb1, acc1);
    }
  }
  __syncthreads();
  stage_W(A2T, lW);
  __syncthreads();
  {
    const u16* sRow = lS0 + arow * WSTR + q * 8;
    bf16x8 fs0 = *(const bf16x8*)(sRow);
    bf16x8 fs1 = *(const bf16x8*)(sRow + 32);
    mm4(lW, m16, q, fs0, fs1, acc0);              // (cinv*S) @ A2
    if (two) {
      const u16* sRow1 = lS1 + arow * WSTR + q * 8;
      bf16x8 ft0 = *(const bf16x8*)(sRow1);
      bf16x8 ft1 = *(const bf16x8*)(sRow1 + 32);
      mm4(lW, m16, q, ft0, ft1, acc1);
    }
  }
  #pragma unroll
  for (int nt = 0; nt < 4; ++nt) {
    int c = nt * 16 + m16;
    #pragma unroll
    for (int r_ = 0; r_ < 4; ++r_) {
      int row = w * 16 + q * 4 + r_;
      int gr = R0 + row;
      if (gr < NN) {
        float bias = lB[c] + lG[row] * lB[64 + c];
        float v0 = fmaxf(acc0[nt][r_] + bias, 0.f);
        Hout0[(size_t)gr * 64 + c] = (u16)f2bf(v0);
        if (two) {
          float v1 = fmaxf(acc1[nt][r_] + bias, 0.f);
          Hout1[(size_t)gr * 64 + c] = (u16)f2bf(v1);
        }
      }
    }
  }
}

// ============================ final projection + variance (fused) ============================
__global__ __launch_bounds__(256) void k_final(const u16* __restrict__ HinB,
                                               const u16* __restrict__ WfT,
                                               const float* __restrict__ bfv,
                                               float* __restrict__ outCausal,
                                               float* __restrict__ out_u) {
  __shared__ __align__(16) u16 lT[64 * WSTR];
  __shared__ __align__(16) u16 lW[64 * WSTR];
  __shared__ float lB[64];
  int t = threadIdx.x;
  int R0 = blockIdx.x * 64;
  stage_W(WfT, lW);
  if (t < 64) lB[t] = bfv[t];
  int l = t & 63, w = t >> 6;
  int m16 = l & 15, q = l >> 4;
  float s1[16], s2[16];
  #pragma unroll
  for (int j = 0; j < 16; ++j) { s1[j] = 0.f; s2[j] = 0.f; }

  for (int inst = 0; inst < 5; ++inst) {
    __syncthreads();
    stage_H(HinB + (size_t)inst * SLAB, R0, lT);
    __syncthreads();
    const u16* aRow = lT + (w * 16 + m16) * WSTR + q * 8;
    bf16x8 fa0 = *(const bf16x8*)(aRow);
    bf16x8 fa1 = *(const bf16x8*)(aRow + 32);
    f32x4 acc[4] = {{0.f, 0.f, 0.f, 0.f}, {0.f, 0.f, 0.f, 0.f},
                    {0.f, 0.f, 0.f, 0.f}, {0.f, 0.f, 0.f, 0.f}};
    mm4(lW, m16, q, fa0, fa1, acc);
    #pragma unroll
    for (int nt = 0; nt < 4; ++nt) {
      int c = nt * 16 + m16;
      #pragma unroll
      for (int r_ = 0; r_ < 4; ++r_) {
        float z = acc[nt][r_] + lB[c];
        if (inst == 0) {
          int gr = R0 + w * 16 + q * 4 + r_;
          if (gr < NN) outCausal[(size_t)gr * 64 + c] = z;
        } else {
          s1[nt * 4 + r_] += z;
          s2[nt * 4 + r_] = fmaf(z, z, s2[nt * 4 + r_]);
        }
      }
    }
  }
  #pragma unroll
  for (int r_ = 0; r_ < 4; ++r_) {
    float pr = 0.f;
    #pragma unroll
    for (int nt = 0; nt < 4; ++nt) {
      float a = s1[nt * 4 + r_];
      pr += s2[nt * 4 + r_] - 0.25f * a * a;
    }
    #pragma unroll
    for (int msk = 1; msk < 16; msk <<= 1)
      pr += __shfl_xor(pr, msk, 64);
    if (m16 == 0) {
      int gr = R0 + w * 16 + q * 4 + r_;
      if (gr < NN) out_u[gr] = fmaxf(pr * (1.0f / 3.0f), 1e-6f);
    }
  }
}

// ============================ launch ============================
extern "C" void kernel_launch(void* const* d_in, const int* in_sizes, int n_in,
                              void* d_out, int out_size, void* d_ws, size_t ws_size,
                              hipStream_t stream) {
  const float* x      = (const float*)d_in[0];
  const int*   eidx   = (const int*)d_in[1];
  const void*  mask   = d_in[2];
  const float* Wi     = (const float*)d_in[3];
  const float* bi     = (const float*)d_in[4];
  const float* msg_W  = (const float*)d_in[5];
  const float* msg_b  = (const float*)d_in[6];
  const float* upd_W  = (const float*)d_in[7];
  const float* upd_b  = (const float*)d_in[8];
  const float* Wf     = (const float*)d_in[9];
  const float* bfv    = (const float*)d_in[10];

  const int* src = eidx;
  const int* dst = eidx + EE;

  char* ws = (char*)d_ws;
  size_t off = 0;
  auto alloc = [&](size_t bytes) -> void* {
    void* p = ws + off;
    off += (bytes + 255) & ~(size_t)255;
    return p;
  };

  int*   cnt     = (int*)alloc(NN * sizeof(int));
  float* cinv    = (float*)alloc(NN * sizeof(float));
  int*   row_ptr = (int*)alloc((NN + 1) * sizeof(int));
  int*   cursor  = (int*)alloc(NN * sizeof(int));
  int*   col     = (int*)alloc(EE * sizeof(int));
  int*   bsums   = (int*)alloc(128 * sizeof(int));
  int*   mode_p  = (int*)alloc(sizeof(int));
  u16*   Wu1T    = (u16*)alloc(2 * 4096 * sizeof(u16));
  u16*   A1T     = (u16*)alloc(2 * 4096 * sizeof(u16));
  u16*   A2T     = (u16*)alloc(2 * 4096 * sizeof(u16));
  u16*   WiT     = (u16*)alloc(4096 * sizeof(u16));
  u16*   WfT     = (u16*)alloc(4096 * sizeof(u16));
  float* C1      = (float*)alloc(2 * 64 * sizeof(float));
  u16*   HA      = (u16*)alloc(5 * SLAB * sizeof(u16));   // 64 MB
  u16*   HB      = (u16*)alloc(5 * SLAB * sizeof(u16));   // 64 MB

  float* out_causal = (float*)d_out;
  float* out_u      = (float*)d_out + SLAB;

  // ---- CSR build ----
  k_detect<<<1, 256, 0, stream>>>((const unsigned*)mask, mode_p);
  hipMemsetAsync(cnt, 0, NN * sizeof(int), stream);
  k_count<<<EE / 256, 256, 0, stream>>>(mask, dst, cnt, mode_p);
  const int SCAN_BLKS = (NN + 1023) / 1024;  // 98
  k_scan_a<<<SCAN_BLKS, 256, 0, stream>>>(cnt, bsums);
  k_scan_b<<<1, 128, 0, stream>>>(bsums, SCAN_BLKS, row_ptr + NN);
  k_scan_c<<<SCAN_BLKS, 256, 0, stream>>>(cnt, bsums, row_ptr, cursor, cinv);
  k_fill<<<EE / 256, 256, 0, stream>>>(mask, src, dst, cursor, col, mode_p);

  // ---- weights ----
  k_prep<<<3, 256, 0, stream>>>(msg_W, msg_b, upd_W, Wi, Wf,
                                Wu1T, A1T, A2T, C1, WiT, WfT);

  // ---- 5 batched GNN passes ----
  dim3 g5(GEMM_BX, 5);
  dim3 gl(GEMM_BX, 3);   // instance pairs {0,1},{2,3},{4}
  k_input<<<g5, 256, 0, stream>>>(x, WiT, bi, HA);
  k_layer<<<gl, 256, 0, stream>>>(HA, HB, row_ptr, col, cnt, cinv,
                                  Wu1T, A1T, A2T, upd_b, C1);
  k_layer<<<gl, 256, 0, stream>>>(HB, HA, row_ptr, col, cnt, cinv,
                                  Wu1T + 4096, A1T + 4096, A2T + 4096,
                                  upd_b + 64, C1 + 64);
  k_final<<<GEMM_BX, 256, 0, stream>>>(HA, WfT, bfv, out_causal, out_u);

  (void)in_sizes; (void)n_in; (void)out_size; (void)ws_size;
}